// Round 1
// baseline (899.182 us; speedup 1.0000x reference)
//
#include <hip/hip_runtime.h>
#include <math.h>

typedef _Float16 h16;

#define DEV static __device__ __forceinline__

constexpr int B_ = 8, C_ = 128, L_ = 4096, OUT_ = 128;
constexpr int NCH = 4, DM = 32, DS = 16, DI = 64;
constexpr int NI = 32; // B_*NCH instances

DEV float sigmoidf_(float x) { return 1.f / (1.f + __expf(-x)); }
DEV float siluf_(float x) { return x * sigmoidf_(x); }
DEV float softplusf_(float x) { return (x > 20.f) ? x : log1pf(__expf(x)); }

// ---------------- K1: LayerNorm1, (B,C,L) -> (B,L,C) ----------------
__global__ __launch_bounds__(128) void k1_ln(const float* __restrict__ x,
                                             const float* __restrict__ gn,
                                             const float* __restrict__ bn,
                                             float* __restrict__ XN) {
  int bid = blockIdx.x;
  int b = bid >> 12, t = bid & (L_ - 1);
  int c = threadIdx.x;
  float v = x[((size_t)(b * C_ + c)) * L_ + t];
  float s = v, q = v * v;
#pragma unroll
  for (int o = 1; o < 64; o <<= 1) {
    s += __shfl_xor(s, o);
    q += __shfl_xor(q, o);
  }
  __shared__ float ls[2], lq[2];
  int wid = c >> 6;
  if ((c & 63) == 0) { ls[wid] = s; lq[wid] = q; }
  __syncthreads();
  float S = ls[0] + ls[1], Q = lq[0] + lq[1];
  float m = S * (1.f / 128.f);
  float var = Q * (1.f / 128.f) - m * m;
  float rs = rsqrtf(var + 1e-5f);
  XN[((size_t)(b * L_ + t)) * C_ + c] = (v - m) * rs * gn[c] + bn[c];
}

// ---------------- K_mean: token sums of xn -> SUMXN[b][c] ----------------
__global__ __launch_bounds__(256) void k_mean(const float* __restrict__ XN,
                                              float* __restrict__ SUMXN) {
  int bid = blockIdx.x;
  int b = bid >> 4, seg = bid & 15;
  int t0 = seg * 256;
  int c = threadIdx.x & 127, half = threadIdx.x >> 7;
  const float* xn = XN + (size_t)b * L_ * C_;
  float acc = 0.f;
  for (int r = half; r < 256; r += 2) acc += xn[(size_t)(t0 + r) * C_ + c];
  __shared__ float red[256];
  red[threadIdx.x] = acc;
  __syncthreads();
  if (half == 0) atomicAdd(&SUMXN[b * C_ + c], red[threadIdx.x] + red[threadIdx.x + 128]);
}

// ---------------- K2: in-proj(x half) + conv + silu + x-proj + dt ----------------
__global__ __launch_bounds__(256) void k2_prep(
    const float* __restrict__ in_W, const float* __restrict__ conv_W,
    const float* __restrict__ conv_b, const float* __restrict__ xproj_W,
    const float* __restrict__ dt_W, const float* __restrict__ dt_b,
    const float* __restrict__ XN, h16* __restrict__ SX, h16* __restrict__ SDT,
    h16* __restrict__ SB, h16* __restrict__ SC) {
  int bid = blockIdx.x;
  int i = bid >> 6, tile = bid & 63;
  int b = i >> 2, ch = i & 3;
  int t0 = tile * 64;
  int tid = threadIdx.x;

  __shared__ float uS[67][33];
  __shared__ float preS[67][65];  // xpre, reused for post-conv x
  __shared__ float xdS[64][35];
  __shared__ float inWxS[64][33];
  __shared__ float xprojS[34][65];
  __shared__ float convWS[64][4];
  __shared__ float dtWS[64][2];
  __shared__ float dtbS[64], cbS[64];

  for (int k = tid; k < 64 * 32; k += 256) inWxS[k >> 5][k & 31] = in_W[k];
  for (int k = tid; k < 34 * 64; k += 256) xprojS[k >> 6][k & 63] = xproj_W[k];
  for (int k = tid; k < 256; k += 256) convWS[k >> 2][k & 3] = conv_W[k];
  if (tid < 128) dtWS[tid >> 1][tid & 1] = dt_W[tid];
  if (tid < 64) { dtbS[tid] = dt_b[tid]; cbS[tid] = conv_b[tid]; }
  const float* xn = XN + (size_t)b * L_ * C_ + ch * DM;
  for (int k = tid; k < 67 * 32; k += 256) {
    int r = k >> 5, c = k & 31;
    int tg = t0 - 3 + r;
    uS[r][c] = (tg >= 0) ? xn[(size_t)tg * C_ + c] : 0.f;
  }
  __syncthreads();
  // xpre = u @ in_W[0:64].T
  for (int k = tid; k < 67 * 64; k += 256) {
    int r = k >> 6, d = k & 63;
    float acc = 0.f;
#pragma unroll
    for (int c = 0; c < 32; ++c) acc = fmaf(uS[r][c], inWxS[d][c], acc);
    preS[r][d] = acc;
  }
  __syncthreads();
  // causal depthwise conv + silu (into regs, then reuse preS)
  float convv[16];
  {
    int idx = 0;
    for (int k = tid; k < 4096; k += 256, ++idx) {
      int r = k >> 6, d = k & 63;
      float v = cbS[d];
#pragma unroll
      for (int j = 0; j < 4; ++j) v = fmaf(convWS[d][j], preS[r + j][d], v);
      convv[idx] = siluf_(v);
    }
  }
  __syncthreads();
  {
    int idx = 0;
    for (int k = tid; k < 4096; k += 256, ++idx) {
      int r = k >> 6, d = k & 63;
      preS[r][d] = convv[idx];
    }
  }
  __syncthreads();
  // SX writeout (d-major, coalesced)
  h16* SXp = SX + (size_t)i * DI * L_;
  for (int k = tid; k < 4096; k += 256) {
    int d = k >> 6, r = k & 63;
    SXp[(size_t)d * L_ + t0 + r] = (h16)preS[r][d];
  }
  // x_dbl = x @ xproj.T
  for (int k = tid; k < 64 * 34; k += 256) {
    int r = k / 34, o = k % 34;
    float acc = 0.f;
#pragma unroll
    for (int c = 0; c < 64; ++c) acc = fmaf(preS[r][c], xprojS[o][c], acc);
    xdS[r][o] = acc;
  }
  __syncthreads();
  h16* SDTp = SDT + (size_t)i * DI * L_;
  for (int k = tid; k < 4096; k += 256) {
    int d = k >> 6, r = k & 63;
    float raw = fmaf(xdS[r][0], dtWS[d][0], fmaf(xdS[r][1], dtWS[d][1], dtbS[d]));
    SDTp[(size_t)d * L_ + t0 + r] = (h16)softplusf_(raw);
  }
  h16* SBp = SB + (size_t)i * DS * L_;
  h16* SCp = SC + (size_t)i * DS * L_;
  for (int k = tid; k < 16 * 64; k += 256) {
    int s = k >> 6, r = k & 63;
    SBp[(size_t)s * L_ + t0 + r] = (h16)xdS[r][2 + s];
    SCp[(size_t)s * L_ + t0 + r] = (h16)xdS[r][18 + s];
  }
}

// ---------------- K3: the selective scan ----------------
__global__ __launch_bounds__(256) void k3_scan(
    const float* __restrict__ A_log, const h16* __restrict__ SDT,
    const h16* __restrict__ SX, const h16* __restrict__ SB,
    const h16* __restrict__ SC, float* __restrict__ YS) {
  int bid = blockIdx.x;
  int i = bid >> 2, dg = bid & 3;
  int tid = threadIdx.x;
  int s = tid & 15;
  int d = dg * 16 + (tid >> 4);
  const h16* pdt = SDT + (size_t)(i * DI + d) * L_;
  const h16* px = SX + (size_t)(i * DI + d) * L_;
  const h16* pB = SB + (size_t)(i * DS + s) * L_;
  const h16* pC = SC + (size_t)(i * DS + s) * L_;
  float* pys = YS + (size_t)(i * DI + d) * L_;
  float A = -__expf(A_log[d * DS + s]);
  float h = 0.f;
  union H8 { float4 f4; h16 hh[8]; };
  H8 ndt, nx, nB, nC;
  ndt.f4 = *(const float4*)pdt;
  nx.f4 = *(const float4*)px;
  nB.f4 = *(const float4*)pB;
  nC.f4 = *(const float4*)pC;
  for (int t0 = 0; t0 < L_; t0 += 8) {
    H8 cdt = ndt, cx = nx, cB = nB, cC = nC;
    int tn = (t0 + 8 < L_) ? (t0 + 8) : t0;
    ndt.f4 = *(const float4*)(pdt + tn);
    nx.f4 = *(const float4*)(px + tn);
    nB.f4 = *(const float4*)(pB + tn);
    nC.f4 = *(const float4*)(pC + tn);
    float yv[8];
#pragma unroll
    for (int k = 0; k < 8; ++k) {
      float dt = (float)cdt.hh[k];
      float xv = (float)cx.hh[k];
      float Bv = (float)cB.hh[k];
      float Cv = (float)cC.hh[k];
      float dA = __expf(dt * A);
      h = fmaf(dA, h, dt * xv * Bv);
      float p = h * Cv;
      p += __shfl_xor(p, 1);
      p += __shfl_xor(p, 2);
      p += __shfl_xor(p, 4);
      p += __shfl_xor(p, 8);
      yv[k] = p;
    }
    if (s == 0) {
      *(float4*)(pys + t0) = make_float4(yv[0], yv[1], yv[2], yv[3]);
      *(float4*)(pys + t0 + 4) = make_float4(yv[4], yv[5], yv[6], yv[7]);
    }
  }
}

// ---------------- K5a: y_full = (ys + x*D) * silu(z), + token sums ----------------
__global__ __launch_bounds__(256) void k5a_yfull(
    const float* __restrict__ in_W, const float* __restrict__ D_p,
    const float* __restrict__ XN, const h16* __restrict__ SX,
    float* __restrict__ YS, float* __restrict__ SUMYF) {
  int bid = blockIdx.x;
  int i = bid >> 6, tile = bid & 63;
  int b = i >> 2, ch = i & 3;
  int t0 = tile * 64;
  int tid = threadIdx.x;
  __shared__ float uS[64][33];
  __shared__ float inWzS[64][33];
  __shared__ float DpS[64];
  for (int k = tid; k < 2048; k += 256) inWzS[k >> 5][k & 31] = in_W[2048 + k];
  if (tid < 64) DpS[tid] = D_p[tid];
  const float* xn = XN + (size_t)b * L_ * C_ + ch * DM;
  for (int k = tid; k < 2048; k += 256) {
    int r = k >> 5, c = k & 31;
    uS[r][c] = xn[(size_t)(t0 + r) * C_ + c];
  }
  __syncthreads();
  const h16* px = SX + (size_t)i * DI * L_;
  float* py = YS + (size_t)i * DI * L_;
  float* sy = SUMYF + i * DI;
  for (int k = tid; k < 4096; k += 256) {
    int dd = k >> 6, tt = k & 63;  // dd uniform per wave
    float z = 0.f;
#pragma unroll
    for (int c = 0; c < 32; ++c) z = fmaf(uS[tt][c], inWzS[dd][c], z);
    float sz = siluf_(z);
    size_t idx = (size_t)dd * L_ + t0 + tt;
    float yf = (py[idx] + (float)px[idx] * DpS[dd]) * sz;
    py[idx] = yf;
    float r = yf;
#pragma unroll
    for (int off = 1; off < 64; off <<= 1) r += __shfl_xor(r, off);
    if ((tid & 63) == 0) atomicAdd(&sy[dd], r);
  }
}

// ---------------- K4: SE gates ----------------
__global__ __launch_bounds__(64) void k4_gates(
    const float* __restrict__ out_W, const float* __restrict__ se_W1,
    const float* __restrict__ se_W2, const float* __restrict__ skip_p,
    const float* __restrict__ SUMYF, const float* __restrict__ SUMXN,
    float* __restrict__ GATES) {
  int i = blockIdx.x;
  int b = i >> 2, ch = i & 3;
  int tid = threadIdx.x;
  __shared__ float syS[64], catS[64], seS[2];
  syS[tid] = SUMYF[i * DI + tid];
  __syncthreads();
  float invL = 1.f / (float)L_;
  if (tid < 32) {
    float acc = 0.f;
#pragma unroll
    for (int dd = 0; dd < 64; ++dd) acc = fmaf(syS[dd], out_W[tid * 64 + dd], acc);
    catS[tid] = acc * invL;
  } else {
    int c = tid - 32;
    catS[tid] = skip_p[0] * SUMXN[b * C_ + ch * DM + c] * invL;
  }
  __syncthreads();
  if (tid < 2) {
    float acc = 0.f;
#pragma unroll
    for (int k = 0; k < 64; ++k) acc = fmaf(catS[k], se_W1[tid * 64 + k], acc);
    seS[tid] = fmaxf(acc, 0.f);
  }
  __syncthreads();
  float gg = fmaf(seS[0], se_W2[tid * 2 + 0], seS[1] * se_W2[tid * 2 + 1]);
  GATES[i * DI + tid] = sigmoidf_(gg);
}

// ---------------- K5b: M1 = yfull @ outW.T, gated combine (in place over xn) ----------------
__global__ __launch_bounds__(256) void k5b_combine(
    const float* __restrict__ out_W, const float* __restrict__ skip_p,
    const float* __restrict__ GATES, const float* __restrict__ YS,
    float* __restrict__ XN) {
  int bid = blockIdx.x;
  int i = bid >> 6, tile = bid & 63;
  int b = i >> 2, ch = i & 3;
  int t0 = tile * 64;
  int tid = threadIdx.x;
  __shared__ float outWS[32][65];
  __shared__ float yfT[64][65];
  __shared__ float gS[64];
  for (int k = tid; k < 2048; k += 256) outWS[k >> 6][k & 63] = out_W[k];
  if (tid < 64) gS[tid] = GATES[i * DI + tid];
  const float* py = YS + (size_t)i * DI * L_;
  for (int k = tid; k < 4096; k += 256) {
    int dd = k >> 6, tt = k & 63;
    yfT[dd][tt] = py[(size_t)dd * L_ + t0 + tt];
  }
  __syncthreads();
  float skip = skip_p[0];
  float* xn = XN + (size_t)b * L_ * C_ + ch * DM;
  for (int k = tid; k < 2048; k += 256) {
    int tt = k >> 5, o = k & 31;
    float acc = 0.f;
#pragma unroll
    for (int dd = 0; dd < 64; ++dd) acc = fmaf(yfT[dd][tt], outWS[o][dd], acc);
    size_t a = (size_t)(t0 + tt) * C_ + o;
    xn[a] = gS[o] * acc + gS[32 + o] * skip * xn[a];
  }
}

// ---------------- K6: LN2 + proj + transpose to (B,OUT,H,W) ----------------
__global__ __launch_bounds__(256) void k6_ln_proj(
    const float* __restrict__ gn, const float* __restrict__ bn,
    const float* __restrict__ proj_W, const float* __restrict__ proj_b,
    const float* __restrict__ XN, float* __restrict__ out) {
  int bid = blockIdx.x;
  int b = bid >> 6, tile = bid & 63;
  int t0 = tile * 64;
  int tid = threadIdx.x;
  __shared__ float xmS[64 * 129];
  __shared__ float projS[32 * 128];
  __shared__ float gnS[128], bnS[128];
  if (tid < 128) { gnS[tid] = gn[tid]; bnS[tid] = bn[tid]; }
  const float* xm = XN + (size_t)b * L_ * C_;
  for (int k = tid; k < 8192; k += 256) {
    int tt = k >> 7, c = k & 127;
    xmS[tt * 129 + c] = xm[(size_t)(t0 + tt) * C_ + c];
  }
  __syncthreads();
  {
    int tok = tid >> 2, q = tid & 3;
    float s = 0.f, qq = 0.f;
#pragma unroll
    for (int c0 = 0; c0 < 128; c0 += 4) {
      float v = xmS[tok * 129 + c0 + q];
      s += v;
      qq += v * v;
    }
    s += __shfl_xor(s, 1); qq += __shfl_xor(qq, 1);
    s += __shfl_xor(s, 2); qq += __shfl_xor(qq, 2);
    float m = s * (1.f / 128.f);
    float var = qq * (1.f / 128.f) - m * m;
    float rs = rsqrtf(var + 1e-5f);
#pragma unroll
    for (int c0 = 0; c0 < 128; c0 += 4) {
      int c = c0 + q;
      float v = xmS[tok * 129 + c];
      xmS[tok * 129 + c] = (v - m) * rs * gnS[c] + bnS[c];
    }
  }
  __syncthreads();
  int w = tid >> 6, lane = tid & 63;
  for (int cc = 0; cc < 4; ++cc) {
    const float4* pw4 = (const float4*)(proj_W + cc * 32 * 128);
    for (int k = tid; k < 1024; k += 256) {
      float4 v = pw4[k];
      projS[4 * k] = v.x; projS[4 * k + 1] = v.y;
      projS[4 * k + 2] = v.z; projS[4 * k + 3] = v.w;
    }
    __syncthreads();
#pragma unroll
    for (int kk = 0; kk < 8; ++kk) {
      int ol = w * 8 + kk;
      int o = cc * 32 + ol;
      float acc = proj_b[o];
#pragma unroll
      for (int c = 0; c < 128; ++c) acc = fmaf(xmS[lane * 129 + c], projS[ol * 128 + c], acc);
      out[((size_t)(b * OUT_ + o)) * L_ + t0 + lane] = acc;
    }
    __syncthreads();
  }
}

extern "C" void kernel_launch(void* const* d_in, const int* in_sizes, int n_in,
                              void* d_out, int out_size, void* d_ws, size_t ws_size,
                              hipStream_t stream) {
  const float* x = (const float*)d_in[0];
  const float* norm_g = (const float*)d_in[1];
  const float* norm_b = (const float*)d_in[2];
  const float* proj_W = (const float*)d_in[3];
  const float* proj_b = (const float*)d_in[4];
  const float* skip = (const float*)d_in[5];
  const float* se_W1 = (const float*)d_in[6];
  const float* se_W2 = (const float*)d_in[7];
  const float* in_W = (const float*)d_in[8];
  const float* conv_W = (const float*)d_in[9];
  const float* conv_b = (const float*)d_in[10];
  const float* xproj_W = (const float*)d_in[11];
  const float* dt_W = (const float*)d_in[12];
  const float* dt_b = (const float*)d_in[13];
  const float* A_log = (const float*)d_in[14];
  const float* D_p = (const float*)d_in[15];
  const float* out_W = (const float*)d_in[16];
  float* out = (float*)d_out;

  // workspace layout (~88 MiB)
  float* XN = (float*)d_ws;                       // B*L*C
  float* YS = XN + (size_t)B_ * L_ * C_;          // NI*DI*L
  float* SUMYF = YS + (size_t)NI * DI * L_;       // NI*DI
  float* SUMXN = SUMYF + NI * DI;                 // B*C (contiguous with SUMYF for one memset)
  float* GATES = SUMXN + B_ * C_;                 // NI*DI
  h16* SX = (h16*)(GATES + NI * DI);              // NI*DI*L
  h16* SDT = SX + (size_t)NI * DI * L_;           // NI*DI*L
  h16* SB = SDT + (size_t)NI * DI * L_;           // NI*DS*L
  h16* SC = SB + (size_t)NI * DS * L_;            // NI*DS*L

  hipMemsetAsync(SUMYF, 0, (size_t)(NI * DI + B_ * C_) * sizeof(float), stream);
  k1_ln<<<B_ * L_, 128, 0, stream>>>(x, norm_g, norm_b, XN);
  k_mean<<<B_ * 16, 256, 0, stream>>>(XN, SUMXN);
  k2_prep<<<NI * 64, 256, 0, stream>>>(in_W, conv_W, conv_b, xproj_W, dt_W, dt_b,
                                       XN, SX, SDT, SB, SC);
  k3_scan<<<NI * 4, 256, 0, stream>>>(A_log, SDT, SX, SB, SC, YS);
  k5a_yfull<<<NI * 64, 256, 0, stream>>>(in_W, D_p, XN, SX, YS, SUMYF);
  k4_gates<<<NI, 64, 0, stream>>>(out_W, se_W1, se_W2, skip, SUMYF, SUMXN, GATES);
  k5b_combine<<<NI * 64, 256, 0, stream>>>(out_W, skip, GATES, YS, XN);
  k6_ln_proj<<<B_ * 64, 256, 0, stream>>>(norm_g, norm_b, proj_W, proj_b, XN, out);
}

// Round 2
// 642.305 us; speedup vs baseline: 1.3999x; 1.3999x over previous
//
#include <hip/hip_runtime.h>
#include <math.h>

typedef _Float16 h16;

#define DEV static __device__ __forceinline__

constexpr int B_ = 8, C_ = 128, L_ = 4096, OUT_ = 128;
constexpr int NCH = 4, DM = 32, DS = 16, DI = 64;
constexpr int NI = 32;           // B_*NCH instances
constexpr int NSEG = 16;         // scan segments
constexpr int SEGLEN = L_ / NSEG; // 256
constexpr int PQN = NI * 4 * NSEG * 256; // 524288 entries per plane

DEV float sigmoidf_(float x) { return 1.f / (1.f + __expf(-x)); }
DEV float siluf_(float x) { return x * sigmoidf_(x); }
DEV float softplusf_(float x) { return (x > 20.f) ? x : log1pf(__expf(x)); }

// ---------------- K1: LayerNorm1 (B,C,L)->(B,L,C) + token sums ----------------
__global__ __launch_bounds__(256) void k1_ln(const float* __restrict__ x,
                                             const float* __restrict__ gn,
                                             const float* __restrict__ bn,
                                             float* __restrict__ XN,
                                             float* __restrict__ SUMXN) {
  int bid = blockIdx.x;                 // b*64 + tile
  int b = bid >> 6, tile = bid & 63;
  int t0 = tile * 64;
  int tid = threadIdx.x;
  __shared__ float xT[128][65];
  __shared__ float gnS[128], bnS[128];
  __shared__ float red[256];
  if (tid < 128) { gnS[tid] = gn[tid]; bnS[tid] = bn[tid]; }
  // coalesced load along L
  for (int k = tid; k < 8192; k += 256) {
    int c = k >> 6, tt = k & 63;
    xT[c][tt] = x[((size_t)(b * C_ + c)) * L_ + t0 + tt];
  }
  __syncthreads();
  // LN per token: 4 threads per token
  {
    int tok = tid >> 2, q = tid & 3;
    float s = 0.f, qq = 0.f;
#pragma unroll
    for (int j = 0; j < 32; ++j) {
      float v = xT[q + 4 * j][tok];
      s += v; qq += v * v;
    }
    s += __shfl_xor(s, 1); qq += __shfl_xor(qq, 1);
    s += __shfl_xor(s, 2); qq += __shfl_xor(qq, 2);
    float m = s * (1.f / 128.f);
    float var = qq * (1.f / 128.f) - m * m;
    float rs = rsqrtf(var + 1e-5f);
#pragma unroll
    for (int j = 0; j < 32; ++j) {
      int c = q + 4 * j;
      float v = xT[c][tok];
      xT[c][tok] = (v - m) * rs * gnS[c] + bnS[c];
    }
  }
  __syncthreads();
  // write out (B,L,C) coalesced in c, accumulate per-channel token sums
  float acc = 0.f;
  int cfix = tid & 127;
  for (int k = tid; k < 8192; k += 256) {
    int tt = k >> 7, c = k & 127;  // c == cfix (stride 256 keeps it)
    float v = xT[c][tt];
    XN[((size_t)(b * L_ + t0 + tt)) * C_ + c] = v;
    acc += v;
  }
  red[tid] = acc;
  __syncthreads();
  if (tid < 128) atomicAdd(&SUMXN[b * C_ + cfix], red[tid] + red[tid + 128]);
}

// ---------------- K2: in-proj(x half) + conv + silu + x-proj + dt ----------------
__global__ __launch_bounds__(256) void k2_prep(
    const float* __restrict__ in_W, const float* __restrict__ conv_W,
    const float* __restrict__ conv_b, const float* __restrict__ xproj_W,
    const float* __restrict__ dt_W, const float* __restrict__ dt_b,
    const float* __restrict__ XN, h16* __restrict__ SX, h16* __restrict__ SDT,
    h16* __restrict__ SB, h16* __restrict__ SC) {
  int bid = blockIdx.x;
  int i = bid >> 6, tile = bid & 63;
  int b = i >> 2, ch = i & 3;
  int t0 = tile * 64;
  int tid = threadIdx.x;

  __shared__ float uS[67][33];
  __shared__ float preS[67][65];
  __shared__ float xdS[64][35];
  __shared__ float inWxS[64][33];
  __shared__ float xprojS[34][65];
  __shared__ float convWS[64][4];
  __shared__ float dtWS[64][2];
  __shared__ float dtbS[64], cbS[64];

  for (int k = tid; k < 64 * 32; k += 256) inWxS[k >> 5][k & 31] = in_W[k];
  for (int k = tid; k < 34 * 64; k += 256) xprojS[k >> 6][k & 63] = xproj_W[k];
  for (int k = tid; k < 256; k += 256) convWS[k >> 2][k & 3] = conv_W[k];
  if (tid < 128) dtWS[tid >> 1][tid & 1] = dt_W[tid];
  if (tid < 64) { dtbS[tid] = dt_b[tid]; cbS[tid] = conv_b[tid]; }
  const float* xn = XN + (size_t)b * L_ * C_ + ch * DM;
  for (int k = tid; k < 67 * 32; k += 256) {
    int r = k >> 5, c = k & 31;
    int tg = t0 - 3 + r;
    uS[r][c] = (tg >= 0) ? xn[(size_t)tg * C_ + c] : 0.f;
  }
  __syncthreads();
  for (int k = tid; k < 67 * 64; k += 256) {
    int r = k >> 6, d = k & 63;
    float acc = 0.f;
#pragma unroll
    for (int c = 0; c < 32; ++c) acc = fmaf(uS[r][c], inWxS[d][c], acc);
    preS[r][d] = acc;
  }
  __syncthreads();
  float convv[16];
  {
    int idx = 0;
    for (int k = tid; k < 4096; k += 256, ++idx) {
      int r = k >> 6, d = k & 63;
      float v = cbS[d];
#pragma unroll
      for (int j = 0; j < 4; ++j) v = fmaf(convWS[d][j], preS[r + j][d], v);
      convv[idx] = siluf_(v);
    }
  }
  __syncthreads();
  {
    int idx = 0;
    for (int k = tid; k < 4096; k += 256, ++idx) {
      int r = k >> 6, d = k & 63;
      preS[r][d] = convv[idx];
    }
  }
  __syncthreads();
  h16* SXp = SX + (size_t)i * DI * L_;
  for (int k = tid; k < 4096; k += 256) {
    int d = k >> 6, r = k & 63;
    SXp[(size_t)d * L_ + t0 + r] = (h16)preS[r][d];
  }
  for (int k = tid; k < 64 * 34; k += 256) {
    int r = k / 34, o = k % 34;
    float acc = 0.f;
#pragma unroll
    for (int c = 0; c < 64; ++c) acc = fmaf(preS[r][c], xprojS[o][c], acc);
    xdS[r][o] = acc;
  }
  __syncthreads();
  h16* SDTp = SDT + (size_t)i * DI * L_;
  for (int k = tid; k < 4096; k += 256) {
    int d = k >> 6, r = k & 63;
    float raw = fmaf(xdS[r][0], dtWS[d][0], fmaf(xdS[r][1], dtWS[d][1], dtbS[d]));
    SDTp[(size_t)d * L_ + t0 + r] = (h16)softplusf_(raw);
  }
  h16* SBp = SB + (size_t)i * DS * L_;
  h16* SCp = SC + (size_t)i * DS * L_;
  for (int k = tid; k < 16 * 64; k += 256) {
    int s = k >> 6, r = k & 63;
    SBp[(size_t)s * L_ + t0 + r] = (h16)xdS[r][2 + s];
    SCp[(size_t)s * L_ + t0 + r] = (h16)xdS[r][18 + s];
  }
}

// ---------------- K3a: per-segment local scan -> (P, Q) ----------------
__global__ __launch_bounds__(256) void k3a_seg(
    const float* __restrict__ A_log, const h16* __restrict__ SDT,
    const h16* __restrict__ SX, const h16* __restrict__ SB,
    float* __restrict__ PQ) {
  int bid = blockIdx.x;              // idg*NSEG + seg
  int seg = bid & (NSEG - 1);
  int idg = bid >> 4;
  int i = idg >> 2, dg = idg & 3;
  int tid = threadIdx.x;
  int s = tid & 15, d = dg * 16 + (tid >> 4);
  int t0 = seg * SEGLEN;
  const h16* pdt = SDT + (size_t)(i * DI + d) * L_ + t0;
  const h16* px = SX + (size_t)(i * DI + d) * L_ + t0;
  const h16* pB = SB + (size_t)(i * DS + s) * L_ + t0;
  float A = -__expf(A_log[d * DS + s]);
  float h = 0.f, sdt = 0.f;
  union H8 { float4 f4; h16 hh[8]; };
  H8 ndt, nx, nB;
  ndt.f4 = *(const float4*)pdt;
  nx.f4 = *(const float4*)px;
  nB.f4 = *(const float4*)pB;
  for (int t = 0; t < SEGLEN; t += 8) {
    H8 cdt = ndt, cx = nx, cB = nB;
    int tn = (t + 8 < SEGLEN) ? (t + 8) : t;
    ndt.f4 = *(const float4*)(pdt + tn);
    nx.f4 = *(const float4*)(px + tn);
    nB.f4 = *(const float4*)(pB + tn);
#pragma unroll
    for (int k = 0; k < 8; ++k) {
      float dt = (float)cdt.hh[k];
      float xv = (float)cx.hh[k];
      float Bv = (float)cB.hh[k];
      float e = __expf(dt * A);
      h = fmaf(e, h, dt * xv * Bv);
      sdt += dt;
    }
  }
  int a = bid * 256 + tid;
  PQ[a] = __expf(A * sdt);   // P
  PQ[PQN + a] = h;           // Q
}

// ---------------- K3b: inter-segment scan -> h0 per segment (overlays P) ----------------
__global__ __launch_bounds__(256) void k3b_comb(float* __restrict__ PQ) {
  int idg = blockIdx.x;   // 128 blocks
  int tid = threadIdx.x;
  float H = 0.f;
#pragma unroll
  for (int seg = 0; seg < NSEG; ++seg) {
    int a = (idg * NSEG + seg) * 256 + tid;
    float P = PQ[a], Q = PQ[PQN + a];
    PQ[a] = H;              // h at segment start
    H = fmaf(P, H, Q);
  }
}

// ---------------- K3c: final scan with seeded h0, y output ----------------
__global__ __launch_bounds__(256) void k3c_scan(
    const float* __restrict__ A_log, const h16* __restrict__ SDT,
    const h16* __restrict__ SX, const h16* __restrict__ SB,
    const h16* __restrict__ SC, const float* __restrict__ PQ,
    h16* __restrict__ YS) {
  int bid = blockIdx.x;
  int seg = bid & (NSEG - 1);
  int idg = bid >> 4;
  int i = idg >> 2, dg = idg & 3;
  int tid = threadIdx.x;
  int s = tid & 15, d = dg * 16 + (tid >> 4);
  int t0 = seg * SEGLEN;
  const h16* pdt = SDT + (size_t)(i * DI + d) * L_ + t0;
  const h16* px = SX + (size_t)(i * DI + d) * L_ + t0;
  const h16* pB = SB + (size_t)(i * DS + s) * L_ + t0;
  const h16* pC = SC + (size_t)(i * DS + s) * L_ + t0;
  h16* pys = YS + (size_t)(i * DI + d) * L_ + t0;
  float A = -__expf(A_log[d * DS + s]);
  float h = PQ[bid * 256 + tid];   // seeded h0
  union H8 { float4 f4; h16 hh[8]; };
  H8 ndt, nx, nB, nC;
  ndt.f4 = *(const float4*)pdt;
  nx.f4 = *(const float4*)px;
  nB.f4 = *(const float4*)pB;
  nC.f4 = *(const float4*)pC;
  for (int t = 0; t < SEGLEN; t += 8) {
    H8 cdt = ndt, cx = nx, cB = nB, cC = nC;
    int tn = (t + 8 < SEGLEN) ? (t + 8) : t;
    ndt.f4 = *(const float4*)(pdt + tn);
    nx.f4 = *(const float4*)(px + tn);
    nB.f4 = *(const float4*)(pB + tn);
    nC.f4 = *(const float4*)(pC + tn);
    H8 yo;
#pragma unroll
    for (int k = 0; k < 8; ++k) {
      float dt = (float)cdt.hh[k];
      float xv = (float)cx.hh[k];
      float Bv = (float)cB.hh[k];
      float Cv = (float)cC.hh[k];
      float dA = __expf(dt * A);
      h = fmaf(dA, h, dt * xv * Bv);
      float p = h * Cv;
      p += __shfl_xor(p, 1);
      p += __shfl_xor(p, 2);
      p += __shfl_xor(p, 4);
      p += __shfl_xor(p, 8);
      yo.hh[k] = (h16)p;
    }
    if (s == 0) *(float4*)(pys + t) = yo.f4;
  }
}

// ---------------- K5a: y_full = (ys + x*D) * silu(z), + token sums ----------------
__global__ __launch_bounds__(256) void k5a_yfull(
    const float* __restrict__ in_W, const float* __restrict__ D_p,
    const float* __restrict__ XN, const h16* __restrict__ SX,
    h16* __restrict__ YS, float* __restrict__ SUMYF) {
  int bid = blockIdx.x;
  int i = bid >> 6, tile = bid & 63;
  int b = i >> 2, ch = i & 3;
  int t0 = tile * 64;
  int tid = threadIdx.x;
  __shared__ float uS[64][33];
  __shared__ float inWzS[64][33];
  __shared__ float DpS[64];
  for (int k = tid; k < 2048; k += 256) inWzS[k >> 5][k & 31] = in_W[2048 + k];
  if (tid < 64) DpS[tid] = D_p[tid];
  const float* xn = XN + (size_t)b * L_ * C_ + ch * DM;
  for (int k = tid; k < 2048; k += 256) {
    int r = k >> 5, c = k & 31;
    uS[r][c] = xn[(size_t)(t0 + r) * C_ + c];
  }
  __syncthreads();
  const h16* px = SX + (size_t)i * DI * L_;
  h16* py = YS + (size_t)i * DI * L_;
  float* sy = SUMYF + i * DI;
  for (int k = tid; k < 4096; k += 256) {
    int dd = k >> 6, tt = k & 63;
    float z = 0.f;
#pragma unroll
    for (int c = 0; c < 32; ++c) z = fmaf(uS[tt][c], inWzS[dd][c], z);
    float sz = siluf_(z);
    size_t idx = (size_t)dd * L_ + t0 + tt;
    float yf = ((float)py[idx] + (float)px[idx] * DpS[dd]) * sz;
    py[idx] = (h16)yf;
    float r = yf;
#pragma unroll
    for (int off = 1; off < 64; off <<= 1) r += __shfl_xor(r, off);
    if ((tid & 63) == 0) atomicAdd(&sy[dd], r);
  }
}

// ---------------- K4: SE gates ----------------
__global__ __launch_bounds__(64) void k4_gates(
    const float* __restrict__ out_W, const float* __restrict__ se_W1,
    const float* __restrict__ se_W2, const float* __restrict__ skip_p,
    const float* __restrict__ SUMYF, const float* __restrict__ SUMXN,
    float* __restrict__ GATES) {
  int i = blockIdx.x;
  int b = i >> 2, ch = i & 3;
  int tid = threadIdx.x;
  __shared__ float syS[64], catS[64], seS[2];
  syS[tid] = SUMYF[i * DI + tid];
  __syncthreads();
  float invL = 1.f / (float)L_;
  if (tid < 32) {
    float acc = 0.f;
#pragma unroll
    for (int dd = 0; dd < 64; ++dd) acc = fmaf(syS[dd], out_W[tid * 64 + dd], acc);
    catS[tid] = acc * invL;
  } else {
    int c = tid - 32;
    catS[tid] = skip_p[0] * SUMXN[b * C_ + ch * DM + c] * invL;
  }
  __syncthreads();
  if (tid < 2) {
    float acc = 0.f;
#pragma unroll
    for (int k = 0; k < 64; ++k) acc = fmaf(catS[k], se_W1[tid * 64 + k], acc);
    seS[tid] = fmaxf(acc, 0.f);
  }
  __syncthreads();
  float gg = fmaf(seS[0], se_W2[tid * 2 + 0], seS[1] * se_W2[tid * 2 + 1]);
  GATES[i * DI + tid] = sigmoidf_(gg);
}

// ---------------- K5b: M1 = yfull @ outW.T, gated combine (in place over xn) ----------------
__global__ __launch_bounds__(256) void k5b_combine(
    const float* __restrict__ out_W, const float* __restrict__ skip_p,
    const float* __restrict__ GATES, const h16* __restrict__ YS,
    float* __restrict__ XN) {
  int bid = blockIdx.x;
  int i = bid >> 6, tile = bid & 63;
  int b = i >> 2, ch = i & 3;
  int t0 = tile * 64;
  int tid = threadIdx.x;
  __shared__ float outWS[32][65];
  __shared__ float yfT[64][65];
  __shared__ float gS[64];
  for (int k = tid; k < 2048; k += 256) outWS[k >> 6][k & 63] = out_W[k];
  if (tid < 64) gS[tid] = GATES[i * DI + tid];
  const h16* py = YS + (size_t)i * DI * L_;
  for (int k = tid; k < 4096; k += 256) {
    int dd = k >> 6, tt = k & 63;
    yfT[dd][tt] = (float)py[(size_t)dd * L_ + t0 + tt];
  }
  __syncthreads();
  float skip = skip_p[0];
  float* xn = XN + (size_t)b * L_ * C_ + ch * DM;
  for (int k = tid; k < 2048; k += 256) {
    int tt = k >> 5, o = k & 31;
    float acc = 0.f;
#pragma unroll
    for (int dd = 0; dd < 64; ++dd) acc = fmaf(yfT[dd][tt], outWS[o][dd], acc);
    size_t a = (size_t)(t0 + tt) * C_ + o;
    xn[a] = gS[o] * acc + gS[32 + o] * skip * xn[a];
  }
}

// ---------------- K6: LN2 + proj + transpose to (B,OUT,H,W) ----------------
__global__ __launch_bounds__(256) void k6_ln_proj(
    const float* __restrict__ gn, const float* __restrict__ bn,
    const float* __restrict__ proj_W, const float* __restrict__ proj_b,
    const float* __restrict__ XN, float* __restrict__ out) {
  int bid = blockIdx.x;
  int b = bid >> 6, tile = bid & 63;
  int t0 = tile * 64;
  int tid = threadIdx.x;
  __shared__ float xmS[64 * 129];
  __shared__ float projS[32 * 128];
  __shared__ float gnS[128], bnS[128];
  if (tid < 128) { gnS[tid] = gn[tid]; bnS[tid] = bn[tid]; }
  const float* xm = XN + (size_t)b * L_ * C_;
  for (int k = tid; k < 8192; k += 256) {
    int tt = k >> 7, c = k & 127;
    xmS[tt * 129 + c] = xm[(size_t)(t0 + tt) * C_ + c];
  }
  __syncthreads();
  {
    int tok = tid >> 2, q = tid & 3;
    float s = 0.f, qq = 0.f;
#pragma unroll
    for (int c0 = 0; c0 < 128; c0 += 4) {
      float v = xmS[tok * 129 + c0 + q];
      s += v;
      qq += v * v;
    }
    s += __shfl_xor(s, 1); qq += __shfl_xor(qq, 1);
    s += __shfl_xor(s, 2); qq += __shfl_xor(qq, 2);
    float m = s * (1.f / 128.f);
    float var = qq * (1.f / 128.f) - m * m;
    float rs = rsqrtf(var + 1e-5f);
#pragma unroll
    for (int c0 = 0; c0 < 128; c0 += 4) {
      int c = c0 + q;
      float v = xmS[tok * 129 + c];
      xmS[tok * 129 + c] = (v - m) * rs * gnS[c] + bnS[c];
    }
  }
  __syncthreads();
  int w = tid >> 6, lane = tid & 63;
  for (int cc = 0; cc < 4; ++cc) {
    const float4* pw4 = (const float4*)(proj_W + cc * 32 * 128);
    for (int k = tid; k < 1024; k += 256) {
      float4 v = pw4[k];
      projS[4 * k] = v.x; projS[4 * k + 1] = v.y;
      projS[4 * k + 2] = v.z; projS[4 * k + 3] = v.w;
    }
    __syncthreads();
#pragma unroll
    for (int kk = 0; kk < 8; ++kk) {
      int ol = w * 8 + kk;
      int o = cc * 32 + ol;
      float acc = proj_b[o];
#pragma unroll
      for (int c = 0; c < 128; ++c) acc = fmaf(xmS[lane * 129 + c], projS[ol * 128 + c], acc);
      out[((size_t)(b * OUT_ + o)) * L_ + t0 + lane] = acc;
    }
    __syncthreads();
  }
}

extern "C" void kernel_launch(void* const* d_in, const int* in_sizes, int n_in,
                              void* d_out, int out_size, void* d_ws, size_t ws_size,
                              hipStream_t stream) {
  const float* x = (const float*)d_in[0];
  const float* norm_g = (const float*)d_in[1];
  const float* norm_b = (const float*)d_in[2];
  const float* proj_W = (const float*)d_in[3];
  const float* proj_b = (const float*)d_in[4];
  const float* skip = (const float*)d_in[5];
  const float* se_W1 = (const float*)d_in[6];
  const float* se_W2 = (const float*)d_in[7];
  const float* in_W = (const float*)d_in[8];
  const float* conv_W = (const float*)d_in[9];
  const float* conv_b = (const float*)d_in[10];
  const float* xproj_W = (const float*)d_in[11];
  const float* dt_W = (const float*)d_in[12];
  const float* dt_b = (const float*)d_in[13];
  const float* A_log = (const float*)d_in[14];
  const float* D_p = (const float*)d_in[15];
  const float* out_W = (const float*)d_in[16];
  float* out = (float*)d_out;

  // workspace layout (~80 MiB)
  float* XN = (float*)d_ws;                         // B*L*C = 4194304 f
  float* SUMYF = XN + (size_t)B_ * L_ * C_;         // NI*DI = 2048 f
  float* SUMXN = SUMYF + NI * DI;                   // B*C = 1024 f
  float* GATES = SUMXN + B_ * C_;                   // NI*DI = 2048 f
  float* PQ = GATES + NI * DI;                      // 2*PQN f
  h16* YS = (h16*)(PQ + 2 * (size_t)PQN);           // NI*DI*L h16
  h16* SX = YS + (size_t)NI * DI * L_;              // NI*DI*L
  h16* SDT = SX + (size_t)NI * DI * L_;             // NI*DI*L
  h16* SB = SDT + (size_t)NI * DI * L_;             // NI*DS*L
  h16* SC = SB + (size_t)NI * DS * L_;              // NI*DS*L

  hipMemsetAsync(SUMYF, 0, (size_t)(NI * DI + B_ * C_) * sizeof(float), stream);
  k1_ln<<<B_ * 64, 256, 0, stream>>>(x, norm_g, norm_b, XN, SUMXN);
  k2_prep<<<NI * 64, 256, 0, stream>>>(in_W, conv_W, conv_b, xproj_W, dt_W, dt_b,
                                       XN, SX, SDT, SB, SC);
  k3a_seg<<<NI * 4 * NSEG, 256, 0, stream>>>(A_log, SDT, SX, SB, PQ);
  k3b_comb<<<NI * 4, 256, 0, stream>>>(PQ);
  k3c_scan<<<NI * 4 * NSEG, 256, 0, stream>>>(A_log, SDT, SX, SB, SC, PQ, YS);
  k5a_yfull<<<NI * 64, 256, 0, stream>>>(in_W, D_p, XN, SX, YS, SUMYF);
  k4_gates<<<NI, 64, 0, stream>>>(out_W, se_W1, se_W2, skip, SUMYF, SUMXN, GATES);
  k5b_combine<<<NI * 64, 256, 0, stream>>>(out_W, skip, GATES, YS, XN);
  k6_ln_proj<<<B_ * 64, 256, 0, stream>>>(norm_g, norm_b, proj_W, proj_b, XN, out);
}

// Round 3
// 436.063 us; speedup vs baseline: 2.0620x; 1.4730x over previous
//
#include <hip/hip_runtime.h>
#include <math.h>

typedef _Float16 h16;

#define DEV static __device__ __forceinline__

constexpr int B_ = 8, C_ = 128, L_ = 4096, OUT_ = 128;
constexpr int NCH = 4, DM = 32, DS = 16, DI = 64;
constexpr int NI = 32;           // B_*NCH instances
constexpr int NSEG = 16;         // scan segments
constexpr int SEGLEN = L_ / NSEG; // 256
constexpr int PQN = NI * 4 * NSEG * 256; // 524288 entries per plane

DEV float sigmoidf_(float x) { return 1.f / (1.f + __expf(-x)); }
DEV float siluf_(float x) { return x * sigmoidf_(x); }
DEV float softplusf_(float x) { return (x > 20.f) ? x : log1pf(__expf(x)); }

// ---------------- K1: LayerNorm1 (B,C,L)->(B,L,C) + token sums ----------------
__global__ __launch_bounds__(256) void k1_ln(const float* __restrict__ x,
                                             const float* __restrict__ gn,
                                             const float* __restrict__ bn,
                                             float* __restrict__ XN,
                                             float* __restrict__ SUMXN) {
  int bid = blockIdx.x;                 // b*64 + tile
  int b = bid >> 6, tile = bid & 63;
  int t0 = tile * 64;
  int tid = threadIdx.x;
  __shared__ float xT[128][65];
  __shared__ float gnS[128], bnS[128];
  __shared__ float red[256];
  if (tid < 128) { gnS[tid] = gn[tid]; bnS[tid] = bn[tid]; }
  for (int k = tid; k < 8192; k += 256) {
    int c = k >> 6, tt = k & 63;
    xT[c][tt] = x[((size_t)(b * C_ + c)) * L_ + t0 + tt];
  }
  __syncthreads();
  {
    int tok = tid >> 2, q = tid & 3;
    float s = 0.f, qq = 0.f;
#pragma unroll
    for (int j = 0; j < 32; ++j) {
      float v = xT[q + 4 * j][tok];
      s += v; qq += v * v;
    }
    s += __shfl_xor(s, 1); qq += __shfl_xor(qq, 1);
    s += __shfl_xor(s, 2); qq += __shfl_xor(qq, 2);
    float m = s * (1.f / 128.f);
    float var = qq * (1.f / 128.f) - m * m;
    float rs = rsqrtf(var + 1e-5f);
#pragma unroll
    for (int j = 0; j < 32; ++j) {
      int c = q + 4 * j;
      float v = xT[c][tok];
      xT[c][tok] = (v - m) * rs * gnS[c] + bnS[c];
    }
  }
  __syncthreads();
  float acc = 0.f;
  int cfix = tid & 127;
  for (int k = tid; k < 8192; k += 256) {
    int tt = k >> 7, c = k & 127;
    float v = xT[c][tt];
    XN[((size_t)(b * L_ + t0 + tt)) * C_ + c] = v;
    acc += v;
  }
  red[tid] = acc;
  __syncthreads();
  if (tid < 128) atomicAdd(&SUMXN[b * C_ + cfix], red[tid] + red[tid + 128]);
}

// ---------------- K2: in-proj(x half) + conv + silu + x-proj + dt ----------------
__global__ __launch_bounds__(256) void k2_prep(
    const float* __restrict__ in_W, const float* __restrict__ conv_W,
    const float* __restrict__ conv_b, const float* __restrict__ xproj_W,
    const float* __restrict__ dt_W, const float* __restrict__ dt_b,
    const float* __restrict__ XN, h16* __restrict__ SX, h16* __restrict__ SDT,
    h16* __restrict__ SB, h16* __restrict__ SC) {
  int bid = blockIdx.x;
  int i = bid >> 6, tile = bid & 63;
  int b = i >> 2, ch = i & 3;
  int t0 = tile * 64;
  int tid = threadIdx.x;
  int w = tid >> 6, lane = tid & 63;

  __shared__ float uS[67][36];      // stride 36: b128-aligned, 2-way banks
  __shared__ float preS[67][65];    // odd stride: scalar reads conflict-free
  __shared__ float xdS[64][35];
  __shared__ float inWxS[64][36];
  __shared__ float xprojS[34][68];  // b128-aligned, broadcast reads
  __shared__ float convWS[64][4];
  __shared__ float dtWS[64][2];
  __shared__ float dtbS[64], cbS[64];

  for (int k = tid; k < 64 * 32; k += 256) inWxS[k >> 5][k & 31] = in_W[k];
  for (int k = tid; k < 34 * 64; k += 256) xprojS[k >> 6][k & 63] = xproj_W[k];
  convWS[tid >> 2][tid & 3] = conv_W[tid];
  if (tid < 128) dtWS[tid >> 1][tid & 1] = dt_W[tid];
  if (tid < 64) { dtbS[tid] = dt_b[tid]; cbS[tid] = conv_b[tid]; }
  const float* xn = XN + (size_t)b * L_ * C_ + ch * DM;
  for (int k = tid; k < 67 * 32; k += 256) {
    int r = k >> 5, c = k & 31;
    int tg = t0 - 3 + r;
    uS[r][c] = (tg >= 0) ? xn[(size_t)tg * C_ + c] : 0.f;
  }
  __syncthreads();
  // in-proj main tile: wave w -> d in [w*16,w*16+16); thread 4 rows x 4 d
  {
    int lr = lane >> 2, ld = lane & 3;
    float acc[16];
#pragma unroll
    for (int q = 0; q < 16; ++q) acc[q] = 0.f;
#pragma unroll
    for (int c0 = 0; c0 < 32; c0 += 4) {
      float4 xr[4], wr[4];
#pragma unroll
      for (int j = 0; j < 4; ++j) xr[j] = *(const float4*)&uS[lr * 4 + j][c0];
#pragma unroll
      for (int oi = 0; oi < 4; ++oi) wr[oi] = *(const float4*)&inWxS[w * 16 + ld * 4 + oi][c0];
#pragma unroll
      for (int j = 0; j < 4; ++j)
#pragma unroll
        for (int oi = 0; oi < 4; ++oi) {
          float a = acc[j * 4 + oi];
          a = fmaf(xr[j].x, wr[oi].x, a);
          a = fmaf(xr[j].y, wr[oi].y, a);
          a = fmaf(xr[j].z, wr[oi].z, a);
          a = fmaf(xr[j].w, wr[oi].w, a);
          acc[j * 4 + oi] = a;
        }
    }
#pragma unroll
    for (int j = 0; j < 4; ++j)
#pragma unroll
      for (int oi = 0; oi < 4; ++oi)
        preS[lr * 4 + j][w * 16 + ld * 4 + oi] = acc[j * 4 + oi];
    // halo rows 64..66 (3 rows x 16 d per wave)
    if (lane < 48) {
      int rh = 64 + (lane >> 4), dh = w * 16 + (lane & 15);
      float a = 0.f;
#pragma unroll
      for (int c = 0; c < 32; ++c) a = fmaf(uS[rh][c], inWxS[dh][c], a);
      preS[rh][dh] = a;
    }
  }
  __syncthreads();
  // causal depthwise conv + silu
  float convv[16];
  {
    int idx = 0;
    for (int k = tid; k < 4096; k += 256, ++idx) {
      int r = k >> 6, d = k & 63;
      float v = cbS[d];
#pragma unroll
      for (int j = 0; j < 4; ++j) v = fmaf(convWS[d][j], preS[r + j][d], v);
      convv[idx] = siluf_(v);
    }
  }
  __syncthreads();
  {
    int idx = 0;
    for (int k = tid; k < 4096; k += 256, ++idx) {
      int r = k >> 6, d = k & 63;
      preS[r][d] = convv[idx];
    }
  }
  __syncthreads();
  h16* SXp = SX + (size_t)i * DI * L_;
  for (int k = tid; k < 4096; k += 256) {
    int d = k >> 6, r = k & 63;
    SXp[(size_t)d * L_ + t0 + r] = (h16)preS[r][d];
  }
  // x-proj: lane = row, wave covers a subset of the 34 outputs
  {
    int o0 = (w == 0) ? 0 : (w == 1) ? 9 : (w == 2) ? 18 : 26;
    int no = (w < 2) ? 9 : 8;
    float acc[9];
#pragma unroll
    for (int q = 0; q < 9; ++q) acc[q] = 0.f;
#pragma unroll
    for (int c0 = 0; c0 < 64; c0 += 32) {
      float xr[32];
#pragma unroll
      for (int c = 0; c < 32; ++c) xr[c] = preS[lane][c0 + c];
#pragma unroll
      for (int q = 0; q < 9; ++q) {
        if (q < no) {
          int o = o0 + q;
          float a = acc[q];
#pragma unroll
          for (int c4 = 0; c4 < 32; c4 += 4) {
            float4 wv = *(const float4*)&xprojS[o][c0 + c4];
            a = fmaf(xr[c4], wv.x, a);
            a = fmaf(xr[c4 + 1], wv.y, a);
            a = fmaf(xr[c4 + 2], wv.z, a);
            a = fmaf(xr[c4 + 3], wv.w, a);
          }
          acc[q] = a;
        }
      }
    }
#pragma unroll
    for (int q = 0; q < 9; ++q)
      if (q < no) xdS[lane][o0 + q] = acc[q];
  }
  __syncthreads();
  h16* SDTp = SDT + (size_t)i * DI * L_;
  for (int k = tid; k < 4096; k += 256) {
    int d = k >> 6, r = k & 63;
    float raw = fmaf(xdS[r][0], dtWS[d][0], fmaf(xdS[r][1], dtWS[d][1], dtbS[d]));
    SDTp[(size_t)d * L_ + t0 + r] = (h16)softplusf_(raw);
  }
  h16* SBp = SB + (size_t)i * DS * L_;
  h16* SCp = SC + (size_t)i * DS * L_;
  for (int k = tid; k < 16 * 64; k += 256) {
    int s = k >> 6, r = k & 63;
    SBp[(size_t)s * L_ + t0 + r] = (h16)xdS[r][2 + s];
    SCp[(size_t)s * L_ + t0 + r] = (h16)xdS[r][18 + s];
  }
}

// ---------------- K3a: per-segment local scan -> (P, Q) ----------------
__global__ __launch_bounds__(256) void k3a_seg(
    const float* __restrict__ A_log, const h16* __restrict__ SDT,
    const h16* __restrict__ SX, const h16* __restrict__ SB,
    float* __restrict__ PQ) {
  int bid = blockIdx.x;              // idg*NSEG + seg
  int seg = bid & (NSEG - 1);
  int idg = bid >> 4;
  int i = idg >> 2, dg = idg & 3;
  int tid = threadIdx.x;
  int s = tid & 15, d = dg * 16 + (tid >> 4);
  int t0 = seg * SEGLEN;
  const h16* pdt = SDT + (size_t)(i * DI + d) * L_ + t0;
  const h16* px = SX + (size_t)(i * DI + d) * L_ + t0;
  const h16* pB = SB + (size_t)(i * DS + s) * L_ + t0;
  float A = -__expf(A_log[d * DS + s]);
  float h = 0.f, sdt = 0.f;
  union H8 { float4 f4; h16 hh[8]; };
  H8 ndt, nx, nB;
  ndt.f4 = *(const float4*)pdt;
  nx.f4 = *(const float4*)px;
  nB.f4 = *(const float4*)pB;
  for (int t = 0; t < SEGLEN; t += 8) {
    H8 cdt = ndt, cx = nx, cB = nB;
    int tn = (t + 8 < SEGLEN) ? (t + 8) : t;
    ndt.f4 = *(const float4*)(pdt + tn);
    nx.f4 = *(const float4*)(px + tn);
    nB.f4 = *(const float4*)(pB + tn);
#pragma unroll
    for (int k = 0; k < 8; ++k) {
      float dt = (float)cdt.hh[k];
      float xv = (float)cx.hh[k];
      float Bv = (float)cB.hh[k];
      float e = __expf(dt * A);
      h = fmaf(e, h, dt * xv * Bv);
      sdt += dt;
    }
  }
  int a = bid * 256 + tid;
  PQ[a] = __expf(A * sdt);   // P
  PQ[PQN + a] = h;           // Q
}

// ---------------- K3b: inter-segment scan -> h0 per segment (overlays P) ----------------
__global__ __launch_bounds__(256) void k3b_comb(float* __restrict__ PQ) {
  int idg = blockIdx.x;   // 128 blocks
  int tid = threadIdx.x;
  float H = 0.f;
#pragma unroll
  for (int seg = 0; seg < NSEG; ++seg) {
    int a = (idg * NSEG + seg) * 256 + tid;
    float P = PQ[a], Q = PQ[PQN + a];
    PQ[a] = H;              // h at segment start
    H = fmaf(P, H, Q);
  }
}

// ---------------- K3c: final scan with seeded h0, y output ----------------
__global__ __launch_bounds__(256) void k3c_scan(
    const float* __restrict__ A_log, const h16* __restrict__ SDT,
    const h16* __restrict__ SX, const h16* __restrict__ SB,
    const h16* __restrict__ SC, const float* __restrict__ PQ,
    h16* __restrict__ YS) {
  int bid = blockIdx.x;
  int seg = bid & (NSEG - 1);
  int idg = bid >> 4;
  int i = idg >> 2, dg = idg & 3;
  int tid = threadIdx.x;
  int s = tid & 15, d = dg * 16 + (tid >> 4);
  int t0 = seg * SEGLEN;
  const h16* pdt = SDT + (size_t)(i * DI + d) * L_ + t0;
  const h16* px = SX + (size_t)(i * DI + d) * L_ + t0;
  const h16* pB = SB + (size_t)(i * DS + s) * L_ + t0;
  const h16* pC = SC + (size_t)(i * DS + s) * L_ + t0;
  h16* pys = YS + (size_t)(i * DI + d) * L_ + t0;
  float A = -__expf(A_log[d * DS + s]);
  float h = PQ[bid * 256 + tid];   // seeded h0
  union H8 { float4 f4; h16 hh[8]; };
  H8 ndt, nx, nB, nC;
  ndt.f4 = *(const float4*)pdt;
  nx.f4 = *(const float4*)px;
  nB.f4 = *(const float4*)pB;
  nC.f4 = *(const float4*)pC;
  for (int t = 0; t < SEGLEN; t += 8) {
    H8 cdt = ndt, cx = nx, cB = nB, cC = nC;
    int tn = (t + 8 < SEGLEN) ? (t + 8) : t;
    ndt.f4 = *(const float4*)(pdt + tn);
    nx.f4 = *(const float4*)(px + tn);
    nB.f4 = *(const float4*)(pB + tn);
    nC.f4 = *(const float4*)(pC + tn);
    H8 yo;
#pragma unroll
    for (int k = 0; k < 8; ++k) {
      float dt = (float)cdt.hh[k];
      float xv = (float)cx.hh[k];
      float Bv = (float)cB.hh[k];
      float Cv = (float)cC.hh[k];
      float dA = __expf(dt * A);
      h = fmaf(dA, h, dt * xv * Bv);
      float p = h * Cv;
      p += __shfl_xor(p, 1);
      p += __shfl_xor(p, 2);
      p += __shfl_xor(p, 4);
      p += __shfl_xor(p, 8);
      yo.hh[k] = (h16)p;
    }
    if (s == 0) *(float4*)(pys + t) = yo.f4;
  }
}

// ---------------- K5a: y_full = (ys + x*D) * silu(z), + token sums ----------------
__global__ __launch_bounds__(256) void k5a_yfull(
    const float* __restrict__ in_W, const float* __restrict__ D_p,
    const float* __restrict__ XN, const h16* __restrict__ SX,
    h16* __restrict__ YS, float* __restrict__ SUMYF) {
  int bid = blockIdx.x;
  int i = bid >> 6, tile = bid & 63;
  int b = i >> 2, ch = i & 3;
  int t0 = tile * 64;
  int tid = threadIdx.x;
  int w = tid >> 6, lane = tid & 63;
  __shared__ float uS[64][33];
  __shared__ float inWzS[64][36];
  __shared__ float DpS[64];
  for (int k = tid; k < 2048; k += 256) inWzS[k >> 5][k & 31] = in_W[2048 + k];
  if (tid < 64) DpS[tid] = D_p[tid];
  const float* xn = XN + (size_t)b * L_ * C_ + ch * DM;
  for (int k = tid; k < 2048; k += 256) {
    int r = k >> 5, c = k & 31;
    uS[r][c] = xn[(size_t)(t0 + r) * C_ + c];
  }
  __syncthreads();
  float ur[32];
#pragma unroll
  for (int c = 0; c < 32; ++c) ur[c] = uS[lane][c];
  const h16* px = SX + (size_t)i * DI * L_;
  h16* py = YS + (size_t)i * DI * L_;
  float* sy = SUMYF + i * DI;
  for (int it = 0; it < 16; ++it) {
    int dd = w + it * 4;
    float z = 0.f;
#pragma unroll
    for (int c4 = 0; c4 < 32; c4 += 4) {
      float4 wv = *(const float4*)&inWzS[dd][c4];
      z = fmaf(ur[c4], wv.x, z);
      z = fmaf(ur[c4 + 1], wv.y, z);
      z = fmaf(ur[c4 + 2], wv.z, z);
      z = fmaf(ur[c4 + 3], wv.w, z);
    }
    float sz = siluf_(z);
    size_t idx = (size_t)dd * L_ + t0 + lane;
    float yf = ((float)py[idx] + (float)px[idx] * DpS[dd]) * sz;
    py[idx] = (h16)yf;
    float r = yf;
#pragma unroll
    for (int off = 1; off < 64; off <<= 1) r += __shfl_xor(r, off);
    if (lane == 0) atomicAdd(&sy[dd], r);
  }
}

// ---------------- K4: SE gates ----------------
__global__ __launch_bounds__(64) void k4_gates(
    const float* __restrict__ out_W, const float* __restrict__ se_W1,
    const float* __restrict__ se_W2, const float* __restrict__ skip_p,
    const float* __restrict__ SUMYF, const float* __restrict__ SUMXN,
    float* __restrict__ GATES) {
  int i = blockIdx.x;
  int b = i >> 2, ch = i & 3;
  int tid = threadIdx.x;
  __shared__ float syS[64], catS[64], seS[2];
  syS[tid] = SUMYF[i * DI + tid];
  __syncthreads();
  float invL = 1.f / (float)L_;
  if (tid < 32) {
    float acc = 0.f;
#pragma unroll
    for (int dd = 0; dd < 64; ++dd) acc = fmaf(syS[dd], out_W[tid * 64 + dd], acc);
    catS[tid] = acc * invL;
  } else {
    int c = tid - 32;
    catS[tid] = skip_p[0] * SUMXN[b * C_ + ch * DM + c] * invL;
  }
  __syncthreads();
  if (tid < 2) {
    float acc = 0.f;
#pragma unroll
    for (int k = 0; k < 64; ++k) acc = fmaf(catS[k], se_W1[tid * 64 + k], acc);
    seS[tid] = fmaxf(acc, 0.f);
  }
  __syncthreads();
  float gg = fmaf(seS[0], se_W2[tid * 2 + 0], seS[1] * se_W2[tid * 2 + 1]);
  GATES[i * DI + tid] = sigmoidf_(gg);
}

// ---------------- K5b: M1 = yfull @ outW.T, gated combine (in place over xn) ----------------
__global__ __launch_bounds__(256) void k5b_combine(
    const float* __restrict__ out_W, const float* __restrict__ skip_p,
    const float* __restrict__ GATES, const h16* __restrict__ YS,
    float* __restrict__ XN) {
  int bid = blockIdx.x;
  int i = bid >> 6, tile = bid & 63;
  int b = i >> 2, ch = i & 3;
  int t0 = tile * 64;
  int tid = threadIdx.x;
  int w = tid >> 6, lane = tid & 63;
  __shared__ float outWS[32][68];
  __shared__ float yfT[64][65];
  __shared__ float xnS[64][37];
  __shared__ float gS[64];
  for (int k = tid; k < 2048; k += 256) outWS[k >> 6][k & 63] = out_W[k];
  if (tid < 64) gS[tid] = GATES[i * DI + tid];
  const h16* py = YS + (size_t)i * DI * L_;
  for (int k = tid; k < 4096; k += 256) {
    int dd = k >> 6, tt = k & 63;
    yfT[tt][dd] = (float)py[(size_t)dd * L_ + t0 + tt];
  }
  float* xn = XN + (size_t)b * L_ * C_ + ch * DM;
  for (int k = tid; k < 2048; k += 256) {
    int tt = k >> 5, o = k & 31;
    xnS[tt][o] = xn[(size_t)(t0 + tt) * C_ + o];
  }
  __syncthreads();
  float yr[64];
#pragma unroll
  for (int dd = 0; dd < 64; ++dd) yr[dd] = yfT[lane][dd];
  float skip = skip_p[0];
#pragma unroll
  for (int q = 0; q < 8; ++q) {
    int o = w * 8 + q;
    float a = 0.f;
#pragma unroll
    for (int d4 = 0; d4 < 64; d4 += 4) {
      float4 wv = *(const float4*)&outWS[o][d4];
      a = fmaf(yr[d4], wv.x, a);
      a = fmaf(yr[d4 + 1], wv.y, a);
      a = fmaf(yr[d4 + 2], wv.z, a);
      a = fmaf(yr[d4 + 3], wv.w, a);
    }
    xnS[lane][o] = gS[o] * a + gS[32 + o] * skip * xnS[lane][o];
  }
  __syncthreads();
  for (int k = tid; k < 2048; k += 256) {
    int tt = k >> 5, o = k & 31;
    xn[(size_t)(t0 + tt) * C_ + o] = xnS[tt][o];
  }
}

// ---------------- K6: LN2 + proj + transpose to (B,OUT,H,W) ----------------
__global__ __launch_bounds__(256) void k6_ln_proj(
    const float* __restrict__ gn, const float* __restrict__ bn,
    const float* __restrict__ proj_W, const float* __restrict__ proj_b,
    const float* __restrict__ XN, float* __restrict__ out) {
  int bid = blockIdx.x;
  int b = bid >> 6, tile = bid & 63;
  int t0 = tile * 64;
  int tid = threadIdx.x;
  int w = tid >> 6, lane = tid & 63;
  __shared__ float xmS[64][132];
  __shared__ float projS[64][132];
  __shared__ float gnS[128], bnS[128];
  if (tid < 128) { gnS[tid] = gn[tid]; bnS[tid] = bn[tid]; }
  const float* xm = XN + (size_t)b * L_ * C_;
  for (int k = tid; k < 8192; k += 256) {
    int tt = k >> 7, c = k & 127;
    xmS[tt][c] = xm[(size_t)(t0 + tt) * C_ + c];
  }
  for (int k = tid; k < 8192; k += 256) {
    int o = k >> 7, c = k & 127;
    projS[o][c] = proj_W[k];
  }
  __syncthreads();
  // LN in place
  {
    int tok = tid >> 2, q = tid & 3;
    float s = 0.f, qq = 0.f;
#pragma unroll
    for (int j = 0; j < 32; ++j) {
      float v = xmS[tok][4 * j + q];
      s += v; qq += v * v;
    }
    s += __shfl_xor(s, 1); qq += __shfl_xor(qq, 1);
    s += __shfl_xor(s, 2); qq += __shfl_xor(qq, 2);
    float m = s * (1.f / 128.f);
    float var = qq * (1.f / 128.f) - m * m;
    float rs = rsqrtf(var + 1e-5f);
#pragma unroll
    for (int j = 0; j < 32; ++j) {
      int c = 4 * j + q;
      float v = xmS[tok][c];
      xmS[tok][c] = (v - m) * rs * gnS[c] + bnS[c];
    }
  }
  __syncthreads();
  int lt = lane >> 2, lo = lane & 3;
  for (int phase = 0; phase < 2; ++phase) {
    if (phase == 1) {
      __syncthreads();
      for (int k = tid; k < 8192; k += 256) {
        int o = k >> 7, c = k & 127;
        projS[o][c] = proj_W[8192 + k];
      }
      __syncthreads();
    }
    int obase = phase * 64 + w * 16 + lo * 4;
    float acc[16];
#pragma unroll
    for (int j = 0; j < 4; ++j)
#pragma unroll
      for (int oi = 0; oi < 4; ++oi) acc[j * 4 + oi] = proj_b[obase + oi];
#pragma unroll 4
    for (int c0 = 0; c0 < 128; c0 += 4) {
      float4 xr[4], pr[4];
#pragma unroll
      for (int j = 0; j < 4; ++j) xr[j] = *(const float4*)&xmS[lt * 4 + j][c0];
#pragma unroll
      for (int oi = 0; oi < 4; ++oi) pr[oi] = *(const float4*)&projS[w * 16 + lo * 4 + oi][c0];
#pragma unroll
      for (int j = 0; j < 4; ++j)
#pragma unroll
        for (int oi = 0; oi < 4; ++oi) {
          float a = acc[j * 4 + oi];
          a = fmaf(xr[j].x, pr[oi].x, a);
          a = fmaf(xr[j].y, pr[oi].y, a);
          a = fmaf(xr[j].z, pr[oi].z, a);
          a = fmaf(xr[j].w, pr[oi].w, a);
          acc[j * 4 + oi] = a;
        }
    }
#pragma unroll
    for (int oi = 0; oi < 4; ++oi) {
      int o = obase + oi;
      float4 v = make_float4(acc[0 * 4 + oi], acc[1 * 4 + oi],
                             acc[2 * 4 + oi], acc[3 * 4 + oi]);
      *(float4*)&out[((size_t)(b * OUT_ + o)) * L_ + t0 + lt * 4] = v;
    }
  }
}

extern "C" void kernel_launch(void* const* d_in, const int* in_sizes, int n_in,
                              void* d_out, int out_size, void* d_ws, size_t ws_size,
                              hipStream_t stream) {
  const float* x = (const float*)d_in[0];
  const float* norm_g = (const float*)d_in[1];
  const float* norm_b = (const float*)d_in[2];
  const float* proj_W = (const float*)d_in[3];
  const float* proj_b = (const float*)d_in[4];
  const float* skip = (const float*)d_in[5];
  const float* se_W1 = (const float*)d_in[6];
  const float* se_W2 = (const float*)d_in[7];
  const float* in_W = (const float*)d_in[8];
  const float* conv_W = (const float*)d_in[9];
  const float* conv_b = (const float*)d_in[10];
  const float* xproj_W = (const float*)d_in[11];
  const float* dt_W = (const float*)d_in[12];
  const float* dt_b = (const float*)d_in[13];
  const float* A_log = (const float*)d_in[14];
  const float* D_p = (const float*)d_in[15];
  const float* out_W = (const float*)d_in[16];
  float* out = (float*)d_out;

  float* XN = (float*)d_ws;                         // B*L*C
  float* SUMYF = XN + (size_t)B_ * L_ * C_;         // NI*DI
  float* SUMXN = SUMYF + NI * DI;                   // B*C
  float* GATES = SUMXN + B_ * C_;                   // NI*DI
  float* PQ = GATES + NI * DI;                      // 2*PQN
  h16* YS = (h16*)(PQ + 2 * (size_t)PQN);           // NI*DI*L
  h16* SX = YS + (size_t)NI * DI * L_;              // NI*DI*L
  h16* SDT = SX + (size_t)NI * DI * L_;             // NI*DI*L
  h16* SB = SDT + (size_t)NI * DI * L_;             // NI*DS*L
  h16* SC = SB + (size_t)NI * DS * L_;              // NI*DS*L

  hipMemsetAsync(SUMYF, 0, (size_t)(NI * DI + B_ * C_) * sizeof(float), stream);
  k1_ln<<<B_ * 64, 256, 0, stream>>>(x, norm_g, norm_b, XN, SUMXN);
  k2_prep<<<NI * 64, 256, 0, stream>>>(in_W, conv_W, conv_b, xproj_W, dt_W, dt_b,
                                       XN, SX, SDT, SB, SC);
  k3a_seg<<<NI * 4 * NSEG, 256, 0, stream>>>(A_log, SDT, SX, SB, PQ);
  k3b_comb<<<NI * 4, 256, 0, stream>>>(PQ);
  k3c_scan<<<NI * 4 * NSEG, 256, 0, stream>>>(A_log, SDT, SX, SB, SC, PQ, YS);
  k5a_yfull<<<NI * 64, 256, 0, stream>>>(in_W, D_p, XN, SX, YS, SUMYF);
  k4_gates<<<NI, 64, 0, stream>>>(out_W, se_W1, se_W2, skip, SUMYF, SUMXN, GATES);
  k5b_combine<<<NI * 64, 256, 0, stream>>>(out_W, skip, GATES, YS, XN);
  k6_ln_proj<<<B_ * 64, 256, 0, stream>>>(norm_g, norm_b, proj_W, proj_b, XN, out);
}

// Round 4
// 426.480 us; speedup vs baseline: 2.1084x; 1.0225x over previous
//
#include <hip/hip_runtime.h>
#include <math.h>

typedef _Float16 h16;

#define DEV static __device__ __forceinline__

constexpr int B_ = 8, C_ = 128, L_ = 4096, OUT_ = 128;
constexpr int NCH = 4, DM = 32, DS = 16, DI = 64;
constexpr int NI = 32;           // B_*NCH instances
constexpr int NSEG = 16;         // scan segments
constexpr int SEGLEN = L_ / NSEG; // 256
constexpr int PQN = NI * 4 * NSEG * 256; // 524288 entries per plane

DEV float sigmoidf_(float x) { return 1.f / (1.f + __expf(-x)); }
DEV float siluf_(float x) { return x * sigmoidf_(x); }
DEV float softplusf_(float x) { return (x > 20.f) ? x : log1pf(__expf(x)); }

// DPP-based cross-lane add: runs on VALU pipe (no LDS/bpermute traffic).
// CTRL: 0x121/0x122/0x124/0x128 = row_ror:1/2/4/8 (within 16-lane rows)
//       0xB1 = quad_perm xor1, 0x4E = quad_perm xor2
template <int CTRL>
DEV float dpp_add_(float x) {
  int v = __builtin_amdgcn_update_dpp(0, __float_as_int(x), CTRL, 0xf, 0xf, false);
  return x + __int_as_float(v);
}
// full sum across a 16-lane row (rotation butterfly; all lanes get total)
DEV float row16_sum_(float x) {
  x = dpp_add_<0x121>(x);
  x = dpp_add_<0x122>(x);
  x = dpp_add_<0x124>(x);
  x = dpp_add_<0x128>(x);
  return x;
}

// ---------------- K1: LayerNorm1 (B,C,L)->(B,L,C) + token sums ----------------
__global__ __launch_bounds__(256) void k1_ln(const float* __restrict__ x,
                                             const float* __restrict__ gn,
                                             const float* __restrict__ bn,
                                             float* __restrict__ XN,
                                             float* __restrict__ SUMXN) {
  int bid = blockIdx.x;                 // b*64 + tile
  int b = bid >> 6, tile = bid & 63;
  int t0 = tile * 64;
  int tid = threadIdx.x;
  __shared__ float xT[128][65];
  __shared__ float gnS[128], bnS[128];
  __shared__ float red[256];
  if (tid < 128) { gnS[tid] = gn[tid]; bnS[tid] = bn[tid]; }
  for (int k = tid; k < 8192; k += 256) {
    int c = k >> 6, tt = k & 63;
    xT[c][tt] = x[((size_t)(b * C_ + c)) * L_ + t0 + tt];
  }
  __syncthreads();
  {
    int tok = tid >> 2, q = tid & 3;
    float s = 0.f, qq = 0.f;
#pragma unroll
    for (int j = 0; j < 32; ++j) {
      float v = xT[q + 4 * j][tok];
      s += v; qq += v * v;
    }
    s = dpp_add_<0xB1>(s); qq = dpp_add_<0xB1>(qq);
    s = dpp_add_<0x4E>(s); qq = dpp_add_<0x4E>(qq);
    float m = s * (1.f / 128.f);
    float var = qq * (1.f / 128.f) - m * m;
    float rs = rsqrtf(var + 1e-5f);
#pragma unroll
    for (int j = 0; j < 32; ++j) {
      int c = q + 4 * j;
      float v = xT[c][tok];
      xT[c][tok] = (v - m) * rs * gnS[c] + bnS[c];
    }
  }
  __syncthreads();
  float acc = 0.f;
  int cfix = tid & 127;
  for (int k = tid; k < 8192; k += 256) {
    int tt = k >> 7, c = k & 127;
    float v = xT[c][tt];
    XN[((size_t)(b * L_ + t0 + tt)) * C_ + c] = v;
    acc += v;
  }
  red[tid] = acc;
  __syncthreads();
  if (tid < 128) atomicAdd(&SUMXN[b * C_ + cfix], red[tid] + red[tid + 128]);
}

// ---------------- K2: in-proj(x half) + conv + silu + x-proj + dt ----------------
__global__ __launch_bounds__(256) void k2_prep(
    const float* __restrict__ in_W, const float* __restrict__ conv_W,
    const float* __restrict__ conv_b, const float* __restrict__ xproj_W,
    const float* __restrict__ dt_W, const float* __restrict__ dt_b,
    const float* __restrict__ XN, h16* __restrict__ SX, h16* __restrict__ SDT,
    h16* __restrict__ SB, h16* __restrict__ SC) {
  int bid = blockIdx.x;
  int i = bid >> 6, tile = bid & 63;
  int b = i >> 2, ch = i & 3;
  int t0 = tile * 64;
  int tid = threadIdx.x;
  int w = tid >> 6, lane = tid & 63;

  __shared__ float uS[67][36];      // stride 36: b128-aligned, 2-way banks
  __shared__ float preS[67][65];    // odd stride: scalar reads conflict-free
  __shared__ float xdS[64][35];
  __shared__ float inWxS[64][36];
  __shared__ float xprojS[34][68];  // b128-aligned, broadcast reads
  __shared__ float convWS[64][4];
  __shared__ float dtWS[64][2];
  __shared__ float dtbS[64], cbS[64];

  for (int k = tid; k < 64 * 32; k += 256) inWxS[k >> 5][k & 31] = in_W[k];
  for (int k = tid; k < 34 * 64; k += 256) xprojS[k >> 6][k & 63] = xproj_W[k];
  convWS[tid >> 2][tid & 3] = conv_W[tid];
  if (tid < 128) dtWS[tid >> 1][tid & 1] = dt_W[tid];
  if (tid < 64) { dtbS[tid] = dt_b[tid]; cbS[tid] = conv_b[tid]; }
  const float* xn = XN + (size_t)b * L_ * C_ + ch * DM;
  for (int k = tid; k < 67 * 32; k += 256) {
    int r = k >> 5, c = k & 31;
    int tg = t0 - 3 + r;
    uS[r][c] = (tg >= 0) ? xn[(size_t)tg * C_ + c] : 0.f;
  }
  __syncthreads();
  // in-proj main tile: wave w -> d in [w*16,w*16+16); thread 4 rows x 4 d
  {
    int lr = lane >> 2, ld = lane & 3;
    float acc[16];
#pragma unroll
    for (int q = 0; q < 16; ++q) acc[q] = 0.f;
#pragma unroll
    for (int c0 = 0; c0 < 32; c0 += 4) {
      float4 xr[4], wr[4];
#pragma unroll
      for (int j = 0; j < 4; ++j) xr[j] = *(const float4*)&uS[lr * 4 + j][c0];
#pragma unroll
      for (int oi = 0; oi < 4; ++oi) wr[oi] = *(const float4*)&inWxS[w * 16 + ld * 4 + oi][c0];
#pragma unroll
      for (int j = 0; j < 4; ++j)
#pragma unroll
        for (int oi = 0; oi < 4; ++oi) {
          float a = acc[j * 4 + oi];
          a = fmaf(xr[j].x, wr[oi].x, a);
          a = fmaf(xr[j].y, wr[oi].y, a);
          a = fmaf(xr[j].z, wr[oi].z, a);
          a = fmaf(xr[j].w, wr[oi].w, a);
          acc[j * 4 + oi] = a;
        }
    }
#pragma unroll
    for (int j = 0; j < 4; ++j)
#pragma unroll
      for (int oi = 0; oi < 4; ++oi)
        preS[lr * 4 + j][w * 16 + ld * 4 + oi] = acc[j * 4 + oi];
    // halo rows 64..66 (3 rows x 16 d per wave)
    if (lane < 48) {
      int rh = 64 + (lane >> 4), dh = w * 16 + (lane & 15);
      float a = 0.f;
#pragma unroll
      for (int c = 0; c < 32; ++c) a = fmaf(uS[rh][c], inWxS[dh][c], a);
      preS[rh][dh] = a;
    }
  }
  __syncthreads();
  // causal depthwise conv + silu
  float convv[16];
  {
    int idx = 0;
    for (int k = tid; k < 4096; k += 256, ++idx) {
      int r = k >> 6, d = k & 63;
      float v = cbS[d];
#pragma unroll
      for (int j = 0; j < 4; ++j) v = fmaf(convWS[d][j], preS[r + j][d], v);
      convv[idx] = siluf_(v);
    }
  }
  __syncthreads();
  {
    int idx = 0;
    for (int k = tid; k < 4096; k += 256, ++idx) {
      int r = k >> 6, d = k & 63;
      preS[r][d] = convv[idx];
    }
  }
  __syncthreads();
  h16* SXp = SX + (size_t)i * DI * L_;
  for (int k = tid; k < 4096; k += 256) {
    int d = k >> 6, r = k & 63;
    SXp[(size_t)d * L_ + t0 + r] = (h16)preS[r][d];
  }
  // x-proj: lane = row, wave covers a subset of the 34 outputs
  {
    int o0 = (w == 0) ? 0 : (w == 1) ? 9 : (w == 2) ? 18 : 26;
    int no = (w < 2) ? 9 : 8;
    float acc[9];
#pragma unroll
    for (int q = 0; q < 9; ++q) acc[q] = 0.f;
#pragma unroll
    for (int c0 = 0; c0 < 64; c0 += 32) {
      float xr[32];
#pragma unroll
      for (int c = 0; c < 32; ++c) xr[c] = preS[lane][c0 + c];
#pragma unroll
      for (int q = 0; q < 9; ++q) {
        if (q < no) {
          int o = o0 + q;
          float a = acc[q];
#pragma unroll
          for (int c4 = 0; c4 < 32; c4 += 4) {
            float4 wv = *(const float4*)&xprojS[o][c0 + c4];
            a = fmaf(xr[c4], wv.x, a);
            a = fmaf(xr[c4 + 1], wv.y, a);
            a = fmaf(xr[c4 + 2], wv.z, a);
            a = fmaf(xr[c4 + 3], wv.w, a);
          }
          acc[q] = a;
        }
      }
    }
#pragma unroll
    for (int q = 0; q < 9; ++q)
      if (q < no) xdS[lane][o0 + q] = acc[q];
  }
  __syncthreads();
  h16* SDTp = SDT + (size_t)i * DI * L_;
  for (int k = tid; k < 4096; k += 256) {
    int d = k >> 6, r = k & 63;
    float raw = fmaf(xdS[r][0], dtWS[d][0], fmaf(xdS[r][1], dtWS[d][1], dtbS[d]));
    SDTp[(size_t)d * L_ + t0 + r] = (h16)softplusf_(raw);
  }
  h16* SBp = SB + (size_t)i * DS * L_;
  h16* SCp = SC + (size_t)i * DS * L_;
  for (int k = tid; k < 16 * 64; k += 256) {
    int s = k >> 6, r = k & 63;
    SBp[(size_t)s * L_ + t0 + r] = (h16)xdS[r][2 + s];
    SCp[(size_t)s * L_ + t0 + r] = (h16)xdS[r][18 + s];
  }
}

// ---------------- K3a: per-segment local scan -> (P, Q) ----------------
__global__ __launch_bounds__(256) void k3a_seg(
    const float* __restrict__ A_log, const h16* __restrict__ SDT,
    const h16* __restrict__ SX, const h16* __restrict__ SB,
    float* __restrict__ PQ) {
  int bid = blockIdx.x;              // idg*NSEG + seg
  int seg = bid & (NSEG - 1);
  int idg = bid >> 4;
  int i = idg >> 2, dg = idg & 3;
  int tid = threadIdx.x;
  int s = tid & 15, d = dg * 16 + (tid >> 4);
  int t0 = seg * SEGLEN;
  const h16* pdt = SDT + (size_t)(i * DI + d) * L_ + t0;
  const h16* px = SX + (size_t)(i * DI + d) * L_ + t0;
  const h16* pB = SB + (size_t)(i * DS + s) * L_ + t0;
  float A = -__expf(A_log[d * DS + s]);
  float h = 0.f, sdt = 0.f;
  union H8 { float4 f4; h16 hh[8]; };
  H8 ndt, nx, nB;
  ndt.f4 = *(const float4*)pdt;
  nx.f4 = *(const float4*)px;
  nB.f4 = *(const float4*)pB;
  for (int t = 0; t < SEGLEN; t += 8) {
    H8 cdt = ndt, cx = nx, cB = nB;
    int tn = (t + 8 < SEGLEN) ? (t + 8) : t;
    ndt.f4 = *(const float4*)(pdt + tn);
    nx.f4 = *(const float4*)(px + tn);
    nB.f4 = *(const float4*)(pB + tn);
#pragma unroll
    for (int k = 0; k < 8; ++k) {
      float dt = (float)cdt.hh[k];
      float xv = (float)cx.hh[k];
      float Bv = (float)cB.hh[k];
      float e = __expf(dt * A);
      h = fmaf(e, h, dt * xv * Bv);
      sdt += dt;
    }
  }
  int a = bid * 256 + tid;
  PQ[a] = __expf(A * sdt);   // P
  PQ[PQN + a] = h;           // Q
}

// ---------------- K3b: inter-segment scan -> h0 per segment (overlays P) ----------------
__global__ __launch_bounds__(256) void k3b_comb(float* __restrict__ PQ) {
  int idg = blockIdx.x;   // 128 blocks
  int tid = threadIdx.x;
  float H = 0.f;
#pragma unroll
  for (int seg = 0; seg < NSEG; ++seg) {
    int a = (idg * NSEG + seg) * 256 + tid;
    float P = PQ[a], Q = PQ[PQN + a];
    PQ[a] = H;              // h at segment start
    H = fmaf(P, H, Q);
  }
}

// ---------------- K3c: final scan with seeded h0, y output ----------------
__global__ __launch_bounds__(256) void k3c_scan(
    const float* __restrict__ A_log, const h16* __restrict__ SDT,
    const h16* __restrict__ SX, const h16* __restrict__ SB,
    const h16* __restrict__ SC, const float* __restrict__ PQ,
    h16* __restrict__ YS) {
  int bid = blockIdx.x;
  int seg = bid & (NSEG - 1);
  int idg = bid >> 4;
  int i = idg >> 2, dg = idg & 3;
  int tid = threadIdx.x;
  int s = tid & 15, d = dg * 16 + (tid >> 4);
  int t0 = seg * SEGLEN;
  const h16* pdt = SDT + (size_t)(i * DI + d) * L_ + t0;
  const h16* px = SX + (size_t)(i * DI + d) * L_ + t0;
  const h16* pB = SB + (size_t)(i * DS + s) * L_ + t0;
  const h16* pC = SC + (size_t)(i * DS + s) * L_ + t0;
  h16* pys = YS + (size_t)(i * DI + d) * L_ + t0;
  float A = -__expf(A_log[d * DS + s]);
  float h = PQ[bid * 256 + tid];   // seeded h0
  union H8 { float4 f4; h16 hh[8]; };
  H8 ndt, nx, nB, nC;
  ndt.f4 = *(const float4*)pdt;
  nx.f4 = *(const float4*)px;
  nB.f4 = *(const float4*)pB;
  nC.f4 = *(const float4*)pC;
  for (int t = 0; t < SEGLEN; t += 8) {
    H8 cdt = ndt, cx = nx, cB = nB, cC = nC;
    int tn = (t + 8 < SEGLEN) ? (t + 8) : t;
    ndt.f4 = *(const float4*)(pdt + tn);
    nx.f4 = *(const float4*)(px + tn);
    nB.f4 = *(const float4*)(pB + tn);
    nC.f4 = *(const float4*)(pC + tn);
    H8 yo;
#pragma unroll
    for (int k = 0; k < 8; ++k) {
      float dt = (float)cdt.hh[k];
      float xv = (float)cx.hh[k];
      float Bv = (float)cB.hh[k];
      float Cv = (float)cC.hh[k];
      float dA = __expf(dt * A);
      h = fmaf(dA, h, dt * xv * Bv);
      float p = row16_sum_(h * Cv);   // DPP rotation butterfly, VALU-only
      yo.hh[k] = (h16)p;
    }
    if (s == 0) *(float4*)(pys + t) = yo.f4;
  }
}

// ---------------- K5a: y_full = (ys + x*D) * silu(z), + token sums ----------------
__global__ __launch_bounds__(256) void k5a_yfull(
    const float* __restrict__ in_W, const float* __restrict__ D_p,
    const float* __restrict__ XN, const h16* __restrict__ SX,
    h16* __restrict__ YS, float* __restrict__ SUMYF) {
  int bid = blockIdx.x;
  int i = bid >> 6, tile = bid & 63;
  int b = i >> 2, ch = i & 3;
  int t0 = tile * 64;
  int tid = threadIdx.x;
  int w = tid >> 6, lane = tid & 63;
  __shared__ float uS[64][33];
  __shared__ float inWzS[64][36];
  __shared__ float DpS[64];
  for (int k = tid; k < 2048; k += 256) inWzS[k >> 5][k & 31] = in_W[2048 + k];
  if (tid < 64) DpS[tid] = D_p[tid];
  const float* xn = XN + (size_t)b * L_ * C_ + ch * DM;
  for (int k = tid; k < 2048; k += 256) {
    int r = k >> 5, c = k & 31;
    uS[r][c] = xn[(size_t)(t0 + r) * C_ + c];
  }
  __syncthreads();
  float ur[32];
#pragma unroll
  for (int c = 0; c < 32; ++c) ur[c] = uS[lane][c];
  const h16* px = SX + (size_t)i * DI * L_;
  h16* py = YS + (size_t)i * DI * L_;
  float* sy = SUMYF + i * DI;
  for (int it = 0; it < 16; ++it) {
    int dd = w + it * 4;
    float z = 0.f;
#pragma unroll
    for (int c4 = 0; c4 < 32; c4 += 4) {
      float4 wv = *(const float4*)&inWzS[dd][c4];
      z = fmaf(ur[c4], wv.x, z);
      z = fmaf(ur[c4 + 1], wv.y, z);
      z = fmaf(ur[c4 + 2], wv.z, z);
      z = fmaf(ur[c4 + 3], wv.w, z);
    }
    float sz = siluf_(z);
    size_t idx = (size_t)dd * L_ + t0 + lane;
    float yf = ((float)py[idx] + (float)px[idx] * DpS[dd]) * sz;
    py[idx] = (h16)yf;
    float r = row16_sum_(yf);      // DPP for the 4 in-row levels
    r += __shfl_xor(r, 16);
    r += __shfl_xor(r, 32);
    if (lane == 0) atomicAdd(&sy[dd], r);
  }
}

// ---------------- K4: SE gates ----------------
__global__ __launch_bounds__(64) void k4_gates(
    const float* __restrict__ out_W, const float* __restrict__ se_W1,
    const float* __restrict__ se_W2, const float* __restrict__ skip_p,
    const float* __restrict__ SUMYF, const float* __restrict__ SUMXN,
    float* __restrict__ GATES) {
  int i = blockIdx.x;
  int b = i >> 2, ch = i & 3;
  int tid = threadIdx.x;
  __shared__ float syS[64], catS[64], seS[2];
  syS[tid] = SUMYF[i * DI + tid];
  __syncthreads();
  float invL = 1.f / (float)L_;
  if (tid < 32) {
    float acc = 0.f;
#pragma unroll
    for (int dd = 0; dd < 64; ++dd) acc = fmaf(syS[dd], out_W[tid * 64 + dd], acc);
    catS[tid] = acc * invL;
  } else {
    int c = tid - 32;
    catS[tid] = skip_p[0] * SUMXN[b * C_ + ch * DM + c] * invL;
  }
  __syncthreads();
  if (tid < 2) {
    float acc = 0.f;
#pragma unroll
    for (int k = 0; k < 64; ++k) acc = fmaf(catS[k], se_W1[tid * 64 + k], acc);
    seS[tid] = fmaxf(acc, 0.f);
  }
  __syncthreads();
  float gg = fmaf(seS[0], se_W2[tid * 2 + 0], seS[1] * se_W2[tid * 2 + 1]);
  GATES[i * DI + tid] = sigmoidf_(gg);
}

// ---------------- K5b: M1 = yfull @ outW.T, gated combine (in place over xn) ----------------
__global__ __launch_bounds__(256) void k5b_combine(
    const float* __restrict__ out_W, const float* __restrict__ skip_p,
    const float* __restrict__ GATES, const h16* __restrict__ YS,
    float* __restrict__ XN) {
  int bid = blockIdx.x;
  int i = bid >> 6, tile = bid & 63;
  int b = i >> 2, ch = i & 3;
  int t0 = tile * 64;
  int tid = threadIdx.x;
  int w = tid >> 6, lane = tid & 63;
  __shared__ float outWS[32][68];
  __shared__ float yfT[64][65];
  __shared__ float xnS[64][37];
  __shared__ float gS[64];
  for (int k = tid; k < 2048; k += 256) outWS[k >> 6][k & 63] = out_W[k];
  if (tid < 64) gS[tid] = GATES[i * DI + tid];
  const h16* py = YS + (size_t)i * DI * L_;
  for (int k = tid; k < 4096; k += 256) {
    int dd = k >> 6, tt = k & 63;
    yfT[tt][dd] = (float)py[(size_t)dd * L_ + t0 + tt];
  }
  float* xn = XN + (size_t)b * L_ * C_ + ch * DM;
  for (int k = tid; k < 2048; k += 256) {
    int tt = k >> 5, o = k & 31;
    xnS[tt][o] = xn[(size_t)(t0 + tt) * C_ + o];
  }
  __syncthreads();
  float yr[64];
#pragma unroll
  for (int dd = 0; dd < 64; ++dd) yr[dd] = yfT[lane][dd];
  float skip = skip_p[0];
#pragma unroll
  for (int q = 0; q < 8; ++q) {
    int o = w * 8 + q;
    float a = 0.f;
#pragma unroll
    for (int d4 = 0; d4 < 64; d4 += 4) {
      float4 wv = *(const float4*)&outWS[o][d4];
      a = fmaf(yr[d4], wv.x, a);
      a = fmaf(yr[d4 + 1], wv.y, a);
      a = fmaf(yr[d4 + 2], wv.z, a);
      a = fmaf(yr[d4 + 3], wv.w, a);
    }
    xnS[lane][o] = gS[o] * a + gS[32 + o] * skip * xnS[lane][o];
  }
  __syncthreads();
  for (int k = tid; k < 2048; k += 256) {
    int tt = k >> 5, o = k & 31;
    xn[(size_t)(t0 + tt) * C_ + o] = xnS[tt][o];
  }
}

// ---------------- K6: LN2 + proj + transpose to (B,OUT,H,W) ----------------
__global__ __launch_bounds__(256) void k6_ln_proj(
    const float* __restrict__ gn, const float* __restrict__ bn,
    const float* __restrict__ proj_W, const float* __restrict__ proj_b,
    const float* __restrict__ XN, float* __restrict__ out) {
  int bid = blockIdx.x;
  int b = bid >> 6, tile = bid & 63;
  int t0 = tile * 64;
  int tid = threadIdx.x;
  int w = tid >> 6, lane = tid & 63;
  __shared__ float xmS[64][132];
  __shared__ float projS[64][132];
  __shared__ float gnS[128], bnS[128];
  if (tid < 128) { gnS[tid] = gn[tid]; bnS[tid] = bn[tid]; }
  const float* xm = XN + (size_t)b * L_ * C_;
  for (int k = tid; k < 8192; k += 256) {
    int tt = k >> 7, c = k & 127;
    xmS[tt][c] = xm[(size_t)(t0 + tt) * C_ + c];
  }
  for (int k = tid; k < 8192; k += 256) {
    int o = k >> 7, c = k & 127;
    projS[o][c] = proj_W[k];
  }
  __syncthreads();
  // LN in place
  {
    int tok = tid >> 2, q = tid & 3;
    float s = 0.f, qq = 0.f;
#pragma unroll
    for (int j = 0; j < 32; ++j) {
      float v = xmS[tok][4 * j + q];
      s += v; qq += v * v;
    }
    s = dpp_add_<0xB1>(s); qq = dpp_add_<0xB1>(qq);
    s = dpp_add_<0x4E>(s); qq = dpp_add_<0x4E>(qq);
    float m = s * (1.f / 128.f);
    float var = qq * (1.f / 128.f) - m * m;
    float rs = rsqrtf(var + 1e-5f);
#pragma unroll
    for (int j = 0; j < 32; ++j) {
      int c = 4 * j + q;
      float v = xmS[tok][c];
      xmS[tok][c] = (v - m) * rs * gnS[c] + bnS[c];
    }
  }
  __syncthreads();
  int lt = lane >> 2, lo = lane & 3;
  for (int phase = 0; phase < 2; ++phase) {
    if (phase == 1) {
      __syncthreads();
      for (int k = tid; k < 8192; k += 256) {
        int o = k >> 7, c = k & 127;
        projS[o][c] = proj_W[8192 + k];
      }
      __syncthreads();
    }
    int obase = phase * 64 + w * 16 + lo * 4;
    float acc[16];
#pragma unroll
    for (int j = 0; j < 4; ++j)
#pragma unroll
      for (int oi = 0; oi < 4; ++oi) acc[j * 4 + oi] = proj_b[obase + oi];
#pragma unroll 4
    for (int c0 = 0; c0 < 128; c0 += 4) {
      float4 xr[4], pr[4];
#pragma unroll
      for (int j = 0; j < 4; ++j) xr[j] = *(const float4*)&xmS[lt * 4 + j][c0];
#pragma unroll
      for (int oi = 0; oi < 4; ++oi) pr[oi] = *(const float4*)&projS[w * 16 + lo * 4 + oi][c0];
#pragma unroll
      for (int j = 0; j < 4; ++j)
#pragma unroll
        for (int oi = 0; oi < 4; ++oi) {
          float a = acc[j * 4 + oi];
          a = fmaf(xr[j].x, pr[oi].x, a);
          a = fmaf(xr[j].y, pr[oi].y, a);
          a = fmaf(xr[j].z, pr[oi].z, a);
          a = fmaf(xr[j].w, pr[oi].w, a);
          acc[j * 4 + oi] = a;
        }
    }
#pragma unroll
    for (int oi = 0; oi < 4; ++oi) {
      int o = obase + oi;
      float4 v = make_float4(acc[0 * 4 + oi], acc[1 * 4 + oi],
                             acc[2 * 4 + oi], acc[3 * 4 + oi]);
      *(float4*)&out[((size_t)(b * OUT_ + o)) * L_ + t0 + lt * 4] = v;
    }
  }
}

extern "C" void kernel_launch(void* const* d_in, const int* in_sizes, int n_in,
                              void* d_out, int out_size, void* d_ws, size_t ws_size,
                              hipStream_t stream) {
  const float* x = (const float*)d_in[0];
  const float* norm_g = (const float*)d_in[1];
  const float* norm_b = (const float*)d_in[2];
  const float* proj_W = (const float*)d_in[3];
  const float* proj_b = (const float*)d_in[4];
  const float* skip = (const float*)d_in[5];
  const float* se_W1 = (const float*)d_in[6];
  const float* se_W2 = (const float*)d_in[7];
  const float* in_W = (const float*)d_in[8];
  const float* conv_W = (const float*)d_in[9];
  const float* conv_b = (const float*)d_in[10];
  const float* xproj_W = (const float*)d_in[11];
  const float* dt_W = (const float*)d_in[12];
  const float* dt_b = (const float*)d_in[13];
  const float* A_log = (const float*)d_in[14];
  const float* D_p = (const float*)d_in[15];
  const float* out_W = (const float*)d_in[16];
  float* out = (float*)d_out;

  float* XN = (float*)d_ws;                         // B*L*C
  float* SUMYF = XN + (size_t)B_ * L_ * C_;         // NI*DI
  float* SUMXN = SUMYF + NI * DI;                   // B*C
  float* GATES = SUMXN + B_ * C_;                   // NI*DI
  float* PQ = GATES + NI * DI;                      // 2*PQN
  h16* YS = (h16*)(PQ + 2 * (size_t)PQN);           // NI*DI*L
  h16* SX = YS + (size_t)NI * DI * L_;              // NI*DI*L
  h16* SDT = SX + (size_t)NI * DI * L_;             // NI*DI*L
  h16* SB = SDT + (size_t)NI * DI * L_;             // NI*DS*L
  h16* SC = SB + (size_t)NI * DS * L_;              // NI*DS*L

  hipMemsetAsync(SUMYF, 0, (size_t)(NI * DI + B_ * C_) * sizeof(float), stream);
  k1_ln<<<B_ * 64, 256, 0, stream>>>(x, norm_g, norm_b, XN, SUMXN);
  k2_prep<<<NI * 64, 256, 0, stream>>>(in_W, conv_W, conv_b, xproj_W, dt_W, dt_b,
                                       XN, SX, SDT, SB, SC);
  k3a_seg<<<NI * 4 * NSEG, 256, 0, stream>>>(A_log, SDT, SX, SB, PQ);
  k3b_comb<<<NI * 4, 256, 0, stream>>>(PQ);
  k3c_scan<<<NI * 4 * NSEG, 256, 0, stream>>>(A_log, SDT, SX, SB, SC, PQ, YS);
  k5a_yfull<<<NI * 64, 256, 0, stream>>>(in_W, D_p, XN, SX, YS, SUMYF);
  k4_gates<<<NI, 64, 0, stream>>>(out_W, se_W1, se_W2, skip, SUMYF, SUMXN, GATES);
  k5b_combine<<<NI * 64, 256, 0, stream>>>(out_W, skip, GATES, YS, XN);
  k6_ln_proj<<<B_ * 64, 256, 0, stream>>>(norm_g, norm_b, proj_W, proj_b, XN, out);
}

// Round 5
// 333.195 us; speedup vs baseline: 2.6987x; 1.2800x over previous
//
#include <hip/hip_runtime.h>
#include <math.h>

typedef _Float16 h16;

#define DEV static __device__ __forceinline__

constexpr int B_ = 8, C_ = 128, L_ = 4096, OUT_ = 128;
constexpr int NCH = 4, DM = 32, DS = 16, DI = 64;
constexpr int NI = 32;            // B_*NCH instances
constexpr int NSEG = 64;          // scan segments
constexpr int SL = L_ / NSEG;     // 64 steps per segment

DEV float sigmoidf_(float x) { return 1.f / (1.f + __expf(-x)); }
DEV float siluf_(float x) { return x * sigmoidf_(x); }
DEV float softplusf_(float x) { return (x > 20.f) ? x : log1pf(__expf(x)); }

template <int CTRL>
DEV float dpp_add_(float x) {
  int v = __builtin_amdgcn_update_dpp(0, __float_as_int(x), CTRL, 0xf, 0xf, false);
  return x + __int_as_float(v);
}

// ---------------- K1: LayerNorm1 (B,C,L)->(B,L,C) + token sums ----------------
__global__ __launch_bounds__(256) void k1_ln(const float* __restrict__ x,
                                             const float* __restrict__ gn,
                                             const float* __restrict__ bn,
                                             float* __restrict__ XN,
                                             float* __restrict__ SUMXN) {
  int bid = blockIdx.x;
  int b = bid >> 6, tile = bid & 63;
  int t0 = tile * 64;
  int tid = threadIdx.x;
  __shared__ float xT[128][65];
  __shared__ float gnS[128], bnS[128];
  __shared__ float red[256];
  if (tid < 128) { gnS[tid] = gn[tid]; bnS[tid] = bn[tid]; }
  for (int k = tid; k < 8192; k += 256) {
    int c = k >> 6, tt = k & 63;
    xT[c][tt] = x[((size_t)(b * C_ + c)) * L_ + t0 + tt];
  }
  __syncthreads();
  {
    int tok = tid >> 2, q = tid & 3;
    float s = 0.f, qq = 0.f;
#pragma unroll
    for (int j = 0; j < 32; ++j) {
      float v = xT[q + 4 * j][tok];
      s += v; qq += v * v;
    }
    s = dpp_add_<0xB1>(s); qq = dpp_add_<0xB1>(qq);
    s = dpp_add_<0x4E>(s); qq = dpp_add_<0x4E>(qq);
    float m = s * (1.f / 128.f);
    float var = qq * (1.f / 128.f) - m * m;
    float rs = rsqrtf(var + 1e-5f);
#pragma unroll
    for (int j = 0; j < 32; ++j) {
      int c = q + 4 * j;
      float v = xT[c][tok];
      xT[c][tok] = (v - m) * rs * gnS[c] + bnS[c];
    }
  }
  __syncthreads();
  float acc = 0.f;
  int cfix = tid & 127;
  for (int k = tid; k < 8192; k += 256) {
    int tt = k >> 7, c = k & 127;
    float v = xT[c][tt];
    XN[((size_t)(b * L_ + t0 + tt)) * C_ + c] = v;
    acc += v;
  }
  red[tid] = acc;
  __syncthreads();
  if (tid < 128) atomicAdd(&SUMXN[b * C_ + cfix], red[tid] + red[tid + 128]);
}

// ---------------- K2: in-proj + conv + silu + x-proj + dt (t-major outputs) ----------------
__global__ __launch_bounds__(256) void k2_prep(
    const float* __restrict__ in_W, const float* __restrict__ conv_W,
    const float* __restrict__ conv_b, const float* __restrict__ xproj_W,
    const float* __restrict__ dt_W, const float* __restrict__ dt_b,
    const float* __restrict__ XN, h16* __restrict__ SX2, h16* __restrict__ SDT2,
    h16* __restrict__ SB2, h16* __restrict__ SC2) {
  int bid = blockIdx.x;
  int i = bid >> 6, tile = bid & 63;
  int b = i >> 2, ch = i & 3;
  int t0 = tile * 64;
  int tid = threadIdx.x;
  int w = tid >> 6, lane = tid & 63;

  __shared__ float uS[67][36];
  __shared__ float preS[67][65];
  __shared__ float xdS[64][35];
  __shared__ float inWxS[64][36];
  __shared__ float xprojS[34][68];
  __shared__ float convWS[64][4];
  __shared__ float dtWS[64][2];
  __shared__ float dtbS[64], cbS[64];

  for (int k = tid; k < 64 * 32; k += 256) inWxS[k >> 5][k & 31] = in_W[k];
  for (int k = tid; k < 34 * 64; k += 256) xprojS[k >> 6][k & 63] = xproj_W[k];
  convWS[tid >> 2][tid & 3] = conv_W[tid];
  if (tid < 128) dtWS[tid >> 1][tid & 1] = dt_W[tid];
  if (tid < 64) { dtbS[tid] = dt_b[tid]; cbS[tid] = conv_b[tid]; }
  const float* xn = XN + (size_t)b * L_ * C_ + ch * DM;
  for (int k = tid; k < 67 * 32; k += 256) {
    int r = k >> 5, c = k & 31;
    int tg = t0 - 3 + r;
    uS[r][c] = (tg >= 0) ? xn[(size_t)tg * C_ + c] : 0.f;
  }
  __syncthreads();
  {
    int lr = lane >> 2, ld = lane & 3;
    float acc[16];
#pragma unroll
    for (int q = 0; q < 16; ++q) acc[q] = 0.f;
#pragma unroll
    for (int c0 = 0; c0 < 32; c0 += 4) {
      float4 xr[4], wr[4];
#pragma unroll
      for (int j = 0; j < 4; ++j) xr[j] = *(const float4*)&uS[lr * 4 + j][c0];
#pragma unroll
      for (int oi = 0; oi < 4; ++oi) wr[oi] = *(const float4*)&inWxS[w * 16 + ld * 4 + oi][c0];
#pragma unroll
      for (int j = 0; j < 4; ++j)
#pragma unroll
        for (int oi = 0; oi < 4; ++oi) {
          float a = acc[j * 4 + oi];
          a = fmaf(xr[j].x, wr[oi].x, a);
          a = fmaf(xr[j].y, wr[oi].y, a);
          a = fmaf(xr[j].z, wr[oi].z, a);
          a = fmaf(xr[j].w, wr[oi].w, a);
          acc[j * 4 + oi] = a;
        }
    }
#pragma unroll
    for (int j = 0; j < 4; ++j)
#pragma unroll
      for (int oi = 0; oi < 4; ++oi)
        preS[lr * 4 + j][w * 16 + ld * 4 + oi] = acc[j * 4 + oi];
    if (lane < 48) {
      int rh = 64 + (lane >> 4), dh = w * 16 + (lane & 15);
      float a = 0.f;
#pragma unroll
      for (int c = 0; c < 32; ++c) a = fmaf(uS[rh][c], inWxS[dh][c], a);
      preS[rh][dh] = a;
    }
  }
  __syncthreads();
  float convv[16];
  {
    int idx = 0;
    for (int k = tid; k < 4096; k += 256, ++idx) {
      int r = k >> 6, d = k & 63;
      float v = cbS[d];
#pragma unroll
      for (int j = 0; j < 4; ++j) v = fmaf(convWS[d][j], preS[r + j][d], v);
      convv[idx] = siluf_(v);
    }
  }
  __syncthreads();
  {
    int idx = 0;
    for (int k = tid; k < 4096; k += 256, ++idx) {
      int r = k >> 6, d = k & 63;
      preS[r][d] = convv[idx];
    }
  }
  __syncthreads();
  // SX2 writeout: t-major [i][t][d]
  h16* SXp = SX2 + ((size_t)i * L_ + t0) * DI;
  for (int k = tid; k < 4096; k += 256) {
    int d = k & 63, r = k >> 6;
    SXp[(size_t)r * DI + d] = (h16)preS[r][d];
  }
  // x-proj
  {
    int o0 = (w == 0) ? 0 : (w == 1) ? 9 : (w == 2) ? 18 : 26;
    int no = (w < 2) ? 9 : 8;
    float acc[9];
#pragma unroll
    for (int q = 0; q < 9; ++q) acc[q] = 0.f;
#pragma unroll
    for (int c0 = 0; c0 < 64; c0 += 32) {
      float xr[32];
#pragma unroll
      for (int c = 0; c < 32; ++c) xr[c] = preS[lane][c0 + c];
#pragma unroll
      for (int q = 0; q < 9; ++q) {
        if (q < no) {
          int o = o0 + q;
          float a = acc[q];
#pragma unroll
          for (int c4 = 0; c4 < 32; c4 += 4) {
            float4 wv = *(const float4*)&xprojS[o][c0 + c4];
            a = fmaf(xr[c4], wv.x, a);
            a = fmaf(xr[c4 + 1], wv.y, a);
            a = fmaf(xr[c4 + 2], wv.z, a);
            a = fmaf(xr[c4 + 3], wv.w, a);
          }
          acc[q] = a;
        }
      }
    }
#pragma unroll
    for (int q = 0; q < 9; ++q)
      if (q < no) xdS[lane][o0 + q] = acc[q];
  }
  __syncthreads();
  h16* SDTp = SDT2 + ((size_t)i * L_ + t0) * DI;
  for (int k = tid; k < 4096; k += 256) {
    int d = k & 63, r = k >> 6;
    float raw = fmaf(xdS[r][0], dtWS[d][0], fmaf(xdS[r][1], dtWS[d][1], dtbS[d]));
    SDTp[(size_t)r * DI + d] = (h16)softplusf_(raw);
  }
  h16* SBp = SB2 + ((size_t)i * L_ + t0) * DS;
  h16* SCp = SC2 + ((size_t)i * L_ + t0) * DS;
  for (int k = tid; k < 16 * 64; k += 256) {
    int s = k & 15, r = k >> 4;
    SBp[(size_t)r * DS + s] = (h16)xdS[r][2 + s];
    SCp[(size_t)r * DS + s] = (h16)xdS[r][18 + s];
  }
}

// ---------------- K3a: per-segment local scan (d-per-thread) -> (P, Q) ----------------
__global__ __launch_bounds__(256) void k3a_seg(
    const float* __restrict__ A_log, const h16* __restrict__ SDT2,
    const h16* __restrict__ SX2, const h16* __restrict__ SB2,
    float* __restrict__ Pp, float* __restrict__ Qp) {
  int bid = blockIdx.x;             // i*16 + sg4
  int i = bid >> 4, sg4 = bid & 15;
  int tid = threadIdx.x;
  int w = tid >> 6, lane = tid & 63;
  int seg = sg4 * 4 + w;
  int t0 = seg * SL;
  __shared__ float bS[4][64][20];
  {
    const h16* pb = SB2 + ((size_t)i * L_ + t0 + lane) * DS;
    float4 r0 = *(const float4*)pb;
    float4 r1 = *(const float4*)(pb + 8);
    const h16* h0p = (const h16*)&r0;
    const h16* h1p = (const h16*)&r1;
#pragma unroll
    for (int s = 0; s < 8; ++s) bS[w][lane][s] = (float)h0p[s];
#pragma unroll
    for (int s = 0; s < 8; ++s) bS[w][lane][8 + s] = (float)h1p[s];
  }
  __syncthreads();
  float Av[16];
#pragma unroll
  for (int s = 0; s < 16; ++s) Av[s] = -__expf(A_log[lane * 16 + s]);
  float A0 = Av[0];
  bool okf = true;
#pragma unroll
  for (int s = 0; s < 16; ++s) okf &= fabsf(Av[s] - (float)(s + 1) * A0) <= 1e-4f * fabsf(Av[s]);
  int fastp = __all(okf ? 1 : 0);
  float h[16];
#pragma unroll
  for (int s = 0; s < 16; ++s) h[s] = 0.f;
  float sdt = 0.f;
  const h16* pdt = SDT2 + ((size_t)i * L_ + t0) * DI + lane;
  const h16* pxx = SX2 + ((size_t)i * L_ + t0) * DI + lane;
  float dtc = (float)pdt[0], xvc = (float)pxx[0];
  for (int t = 0; t < SL; ++t) {
    float dt = dtc, xv = xvc;
    if (t < SL - 1) { dtc = (float)pdt[(t + 1) * DI]; xvc = (float)pxx[(t + 1) * DI]; }
    float Bv[16];
    const float* row = &bS[w][t][0];
#pragma unroll
    for (int j = 0; j < 4; ++j) *(float4*)&Bv[4 * j] = *(const float4*)(row + 4 * j);
    float dtx = dt * xv;
    float dA[16];
    if (fastp) {
      float E = __expf(A0 * dt);
      dA[0] = E;
#pragma unroll
      for (int s = 1; s < 16; ++s) dA[s] = dA[s - 1] * E;
    } else {
#pragma unroll
      for (int s = 0; s < 16; ++s) dA[s] = __expf(Av[s] * dt);
    }
#pragma unroll
    for (int s = 0; s < 16; ++s) h[s] = fmaf(dA[s], h[s], dtx * Bv[s]);
    sdt += dt;
  }
  float P[16];
  if (fastp) {
    float E = __expf(A0 * sdt);
    P[0] = E;
#pragma unroll
    for (int s = 1; s < 16; ++s) P[s] = P[s - 1] * E;
  } else {
#pragma unroll
    for (int s = 0; s < 16; ++s) P[s] = __expf(Av[s] * sdt);
  }
  size_t base = (((size_t)i * DI + lane) * NSEG + seg) * DS;
#pragma unroll
  for (int j = 0; j < 4; ++j) {
    *(float4*)(Pp + base + 4 * j) = *(float4*)&P[4 * j];
    *(float4*)(Qp + base + 4 * j) = *(float4*)&h[4 * j];
  }
}

// ---------------- K3b: inter-segment scan -> h0 per segment (overlays P) ----------------
__global__ __launch_bounds__(256) void k3b_comb(float* __restrict__ Pp,
                                                const float* __restrict__ Qp) {
  int g = blockIdx.x * 256 + threadIdx.x;  // 32768 = NI*DI*DS
  int s = g & 15;
  int r = g >> 4;          // over NI*DI
  size_t base = (size_t)r * NSEG * DS + s;
  float H = 0.f;
  for (int seg = 0; seg < NSEG; ++seg) {
    size_t a = base + (size_t)seg * DS;
    float P = Pp[a], Q = Qp[a];
    Pp[a] = H;
    H = fmaf(P, H, Q);
  }
}

// ---------------- K3c: final scan, fused with z-gate/D-term/token-sums ----------------
__global__ __launch_bounds__(256) void k3c_scan(
    const float* __restrict__ A_log, const h16* __restrict__ SDT2,
    const h16* __restrict__ SX2, const h16* __restrict__ SB2,
    const h16* __restrict__ SC2, const float* __restrict__ XN,
    const float* __restrict__ in_W, const float* __restrict__ D_p,
    const float* __restrict__ H0p, h16* __restrict__ YS2,
    float* __restrict__ SUMYF) {
  int bid = blockIdx.x;             // i*16 + sg4
  int i = bid >> 4, sg4 = bid & 15;
  int b = i >> 2, ch = i & 3;
  int tid = threadIdx.x;
  int w = tid >> 6, lane = tid & 63;
  int seg = sg4 * 4 + w;
  int t0 = seg * SL;
  __shared__ float rowS[4][64][68];   // [w][t][ B16 | C16 | u32 ] + pad
  {
    const h16* pb = SB2 + ((size_t)i * L_ + t0 + lane) * DS;
    const h16* pc = SC2 + ((size_t)i * L_ + t0 + lane) * DS;
    float4 r0 = *(const float4*)pb;
    float4 r1 = *(const float4*)(pb + 8);
    float4 r2 = *(const float4*)pc;
    float4 r3 = *(const float4*)(pc + 8);
    const h16* hp0 = (const h16*)&r0;
    const h16* hp1 = (const h16*)&r1;
    const h16* hp2 = (const h16*)&r2;
    const h16* hp3 = (const h16*)&r3;
#pragma unroll
    for (int s = 0; s < 8; ++s) {
      rowS[w][lane][s] = (float)hp0[s];
      rowS[w][lane][8 + s] = (float)hp1[s];
      rowS[w][lane][16 + s] = (float)hp2[s];
      rowS[w][lane][24 + s] = (float)hp3[s];
    }
    const float* pu = XN + ((size_t)(b * L_ + t0 + lane)) * C_ + ch * DM;
#pragma unroll
    for (int j = 0; j < 8; ++j)
      *(float4*)&rowS[w][lane][32 + 4 * j] = *(const float4*)(pu + 4 * j);
  }
  __syncthreads();
  float Av[16];
#pragma unroll
  for (int s = 0; s < 16; ++s) Av[s] = -__expf(A_log[lane * 16 + s]);
  float A0 = Av[0];
  bool okf = true;
#pragma unroll
  for (int s = 0; s < 16; ++s) okf &= fabsf(Av[s] - (float)(s + 1) * A0) <= 1e-4f * fabsf(Av[s]);
  int fastp = __all(okf ? 1 : 0);
  float4 wz[8];
#pragma unroll
  for (int j = 0; j < 8; ++j) wz[j] = *(const float4*)(in_W + 2048 + lane * 32 + 4 * j);
  float Dp = D_p[lane];
  float h[16];
  {
    size_t base = (((size_t)i * DI + lane) * NSEG + seg) * DS;
#pragma unroll
    for (int j = 0; j < 4; ++j) *(float4*)&h[4 * j] = *(const float4*)(H0p + base + 4 * j);
  }
  const h16* pdt = SDT2 + ((size_t)i * L_ + t0) * DI + lane;
  const h16* pxx = SX2 + ((size_t)i * L_ + t0) * DI + lane;
  h16* pys = YS2 + ((size_t)i * L_ + t0) * DI + lane;
  float dtc = (float)pdt[0], xvc = (float)pxx[0];
  float sum = 0.f;
  for (int t = 0; t < SL; ++t) {
    float dt = dtc, xv = xvc;
    if (t < SL - 1) { dtc = (float)pdt[(t + 1) * DI]; xvc = (float)pxx[(t + 1) * DI]; }
    const float* row = &rowS[w][t][0];
    float Bv[16], Cv[16];
#pragma unroll
    for (int j = 0; j < 4; ++j) {
      *(float4*)&Bv[4 * j] = *(const float4*)(row + 4 * j);
      *(float4*)&Cv[4 * j] = *(const float4*)(row + 16 + 4 * j);
    }
    float dtx = dt * xv;
    float dA[16];
    if (fastp) {
      float E = __expf(A0 * dt);
      dA[0] = E;
#pragma unroll
      for (int s = 1; s < 16; ++s) dA[s] = dA[s - 1] * E;
    } else {
#pragma unroll
      for (int s = 0; s < 16; ++s) dA[s] = __expf(Av[s] * dt);
    }
    float y = 0.f;
#pragma unroll
    for (int s = 0; s < 16; ++s) {
      h[s] = fmaf(dA[s], h[s], dtx * Bv[s]);
      y = fmaf(h[s], Cv[s], y);
    }
    float z = 0.f;
#pragma unroll
    for (int j = 0; j < 8; ++j) {
      float4 u4 = *(const float4*)(row + 32 + 4 * j);
      z = fmaf(u4.x, wz[j].x, z);
      z = fmaf(u4.y, wz[j].y, z);
      z = fmaf(u4.z, wz[j].z, z);
      z = fmaf(u4.w, wz[j].w, z);
    }
    float yf = (y + xv * Dp) * siluf_(z);
    pys[(size_t)t * DI] = (h16)yf;
    sum += yf;
  }
  atomicAdd(&SUMYF[i * DI + lane], sum);
}

// ---------------- K4: SE gates ----------------
__global__ __launch_bounds__(64) void k4_gates(
    const float* __restrict__ out_W, const float* __restrict__ se_W1,
    const float* __restrict__ se_W2, const float* __restrict__ skip_p,
    const float* __restrict__ SUMYF, const float* __restrict__ SUMXN,
    float* __restrict__ GATES) {
  int i = blockIdx.x;
  int b = i >> 2, ch = i & 3;
  int tid = threadIdx.x;
  __shared__ float syS[64], catS[64], seS[2];
  syS[tid] = SUMYF[i * DI + tid];
  __syncthreads();
  float invL = 1.f / (float)L_;
  if (tid < 32) {
    float acc = 0.f;
#pragma unroll
    for (int dd = 0; dd < 64; ++dd) acc = fmaf(syS[dd], out_W[tid * 64 + dd], acc);
    catS[tid] = acc * invL;
  } else {
    int c = tid - 32;
    catS[tid] = skip_p[0] * SUMXN[b * C_ + ch * DM + c] * invL;
  }
  __syncthreads();
  if (tid < 2) {
    float acc = 0.f;
#pragma unroll
    for (int k = 0; k < 64; ++k) acc = fmaf(catS[k], se_W1[tid * 64 + k], acc);
    seS[tid] = fmaxf(acc, 0.f);
  }
  __syncthreads();
  float gg = fmaf(seS[0], se_W2[tid * 2 + 0], seS[1] * se_W2[tid * 2 + 1]);
  GATES[i * DI + tid] = sigmoidf_(gg);
}

// ---------------- K5b: M1 = yfull @ outW.T, gated combine (in place over xn) ----------------
__global__ __launch_bounds__(256) void k5b_combine(
    const float* __restrict__ out_W, const float* __restrict__ skip_p,
    const float* __restrict__ GATES, const h16* __restrict__ YS2,
    float* __restrict__ XN) {
  int bid = blockIdx.x;
  int i = bid >> 6, tile = bid & 63;
  int b = i >> 2, ch = i & 3;
  int t0 = tile * 64;
  int tid = threadIdx.x;
  int w = tid >> 6, lane = tid & 63;
  __shared__ float outWS[32][68];
  __shared__ float yfT[64][65];
  __shared__ float xnS[64][37];
  __shared__ float gS[64];
  for (int k = tid; k < 2048; k += 256) outWS[k >> 6][k & 63] = out_W[k];
  if (tid < 64) gS[tid] = GATES[i * DI + tid];
  const h16* py = YS2 + ((size_t)i * L_ + t0) * DI;
  for (int k = tid; k < 4096; k += 256) {
    int dd = k & 63, tt = k >> 6;
    yfT[tt][dd] = (float)py[(size_t)tt * DI + dd];
  }
  float* xn = XN + (size_t)b * L_ * C_ + ch * DM;
  for (int k = tid; k < 2048; k += 256) {
    int tt = k >> 5, o = k & 31;
    xnS[tt][o] = xn[(size_t)(t0 + tt) * C_ + o];
  }
  __syncthreads();
  float yr[64];
#pragma unroll
  for (int dd = 0; dd < 64; ++dd) yr[dd] = yfT[lane][dd];
  float skip = skip_p[0];
#pragma unroll
  for (int q = 0; q < 8; ++q) {
    int o = w * 8 + q;
    float a = 0.f;
#pragma unroll
    for (int d4 = 0; d4 < 64; d4 += 4) {
      float4 wv = *(const float4*)&outWS[o][d4];
      a = fmaf(yr[d4], wv.x, a);
      a = fmaf(yr[d4 + 1], wv.y, a);
      a = fmaf(yr[d4 + 2], wv.z, a);
      a = fmaf(yr[d4 + 3], wv.w, a);
    }
    xnS[lane][o] = gS[o] * a + gS[32 + o] * skip * xnS[lane][o];
  }
  __syncthreads();
  for (int k = tid; k < 2048; k += 256) {
    int tt = k >> 5, o = k & 31;
    xn[(size_t)(t0 + tt) * C_ + o] = xnS[tt][o];
  }
}

// ---------------- K6: LN2 + proj + transpose to (B,OUT,H,W) ----------------
__global__ __launch_bounds__(256) void k6_ln_proj(
    const float* __restrict__ gn, const float* __restrict__ bn,
    const float* __restrict__ proj_W, const float* __restrict__ proj_b,
    const float* __restrict__ XN, float* __restrict__ out) {
  int bid = blockIdx.x;
  int b = bid >> 6, tile = bid & 63;
  int t0 = tile * 64;
  int tid = threadIdx.x;
  int w = tid >> 6, lane = tid & 63;
  __shared__ float xmS[64][132];
  __shared__ float projS[64][132];
  __shared__ float gnS[128], bnS[128];
  if (tid < 128) { gnS[tid] = gn[tid]; bnS[tid] = bn[tid]; }
  const float* xm = XN + (size_t)b * L_ * C_;
  for (int k = tid; k < 8192; k += 256) {
    int tt = k >> 7, c = k & 127;
    xmS[tt][c] = xm[(size_t)(t0 + tt) * C_ + c];
  }
  for (int k = tid; k < 8192; k += 256) {
    int o = k >> 7, c = k & 127;
    projS[o][c] = proj_W[k];
  }
  __syncthreads();
  {
    int tok = tid >> 2, q = tid & 3;
    float s = 0.f, qq = 0.f;
#pragma unroll
    for (int j = 0; j < 32; ++j) {
      float v = xmS[tok][4 * j + q];
      s += v; qq += v * v;
    }
    s = dpp_add_<0xB1>(s); qq = dpp_add_<0xB1>(qq);
    s = dpp_add_<0x4E>(s); qq = dpp_add_<0x4E>(qq);
    float m = s * (1.f / 128.f);
    float var = qq * (1.f / 128.f) - m * m;
    float rs = rsqrtf(var + 1e-5f);
#pragma unroll
    for (int j = 0; j < 32; ++j) {
      int c = 4 * j + q;
      float v = xmS[tok][c];
      xmS[tok][c] = (v - m) * rs * gnS[c] + bnS[c];
    }
  }
  __syncthreads();
  int lt = lane >> 2, lo = lane & 3;
  for (int phase = 0; phase < 2; ++phase) {
    if (phase == 1) {
      __syncthreads();
      for (int k = tid; k < 8192; k += 256) {
        int o = k >> 7, c = k & 127;
        projS[o][c] = proj_W[8192 + k];
      }
      __syncthreads();
    }
    int obase = phase * 64 + w * 16 + lo * 4;
    float acc[16];
#pragma unroll
    for (int j = 0; j < 4; ++j)
#pragma unroll
      for (int oi = 0; oi < 4; ++oi) acc[j * 4 + oi] = proj_b[obase + oi];
#pragma unroll 4
    for (int c0 = 0; c0 < 128; c0 += 4) {
      float4 xr[4], pr[4];
#pragma unroll
      for (int j = 0; j < 4; ++j) xr[j] = *(const float4*)&xmS[lt * 4 + j][c0];
#pragma unroll
      for (int oi = 0; oi < 4; ++oi) pr[oi] = *(const float4*)&projS[w * 16 + lo * 4 + oi][c0];
#pragma unroll
      for (int j = 0; j < 4; ++j)
#pragma unroll
        for (int oi = 0; oi < 4; ++oi) {
          float a = acc[j * 4 + oi];
          a = fmaf(xr[j].x, pr[oi].x, a);
          a = fmaf(xr[j].y, pr[oi].y, a);
          a = fmaf(xr[j].z, pr[oi].z, a);
          a = fmaf(xr[j].w, pr[oi].w, a);
          acc[j * 4 + oi] = a;
        }
    }
#pragma unroll
    for (int oi = 0; oi < 4; ++oi) {
      int o = obase + oi;
      float4 v = make_float4(acc[0 * 4 + oi], acc[1 * 4 + oi],
                             acc[2 * 4 + oi], acc[3 * 4 + oi]);
      *(float4*)&out[((size_t)(b * OUT_ + o)) * L_ + t0 + lt * 4] = v;
    }
  }
}

extern "C" void kernel_launch(void* const* d_in, const int* in_sizes, int n_in,
                              void* d_out, int out_size, void* d_ws, size_t ws_size,
                              hipStream_t stream) {
  const float* x = (const float*)d_in[0];
  const float* norm_g = (const float*)d_in[1];
  const float* norm_b = (const float*)d_in[2];
  const float* proj_W = (const float*)d_in[3];
  const float* proj_b = (const float*)d_in[4];
  const float* skip = (const float*)d_in[5];
  const float* se_W1 = (const float*)d_in[6];
  const float* se_W2 = (const float*)d_in[7];
  const float* in_W = (const float*)d_in[8];
  const float* conv_W = (const float*)d_in[9];
  const float* conv_b = (const float*)d_in[10];
  const float* xproj_W = (const float*)d_in[11];
  const float* dt_W = (const float*)d_in[12];
  const float* dt_b = (const float*)d_in[13];
  const float* A_log = (const float*)d_in[14];
  const float* D_p = (const float*)d_in[15];
  const float* out_W = (const float*)d_in[16];
  float* out = (float*)d_out;

  // workspace (~92 MiB)
  float* XN = (float*)d_ws;                         // B*L*C f32
  float* SUMYF = XN + (size_t)B_ * L_ * C_;         // NI*DI
  float* SUMXN = SUMYF + NI * DI;                   // B*C
  float* GATES = SUMXN + B_ * C_;                   // NI*DI
  float* Pp = GATES + NI * DI;                      // NI*DI*NSEG*DS f32
  float* Qp = Pp + (size_t)NI * DI * NSEG * DS;
  h16* YS2 = (h16*)(Qp + (size_t)NI * DI * NSEG * DS);  // NI*L*DI h16
  h16* SX2 = YS2 + (size_t)NI * L_ * DI;
  h16* SDT2 = SX2 + (size_t)NI * L_ * DI;
  h16* SB2 = SDT2 + (size_t)NI * L_ * DI;           // NI*L*DS h16
  h16* SC2 = SB2 + (size_t)NI * L_ * DS;

  hipMemsetAsync(SUMYF, 0, (size_t)(NI * DI + B_ * C_) * sizeof(float), stream);
  k1_ln<<<B_ * 64, 256, 0, stream>>>(x, norm_g, norm_b, XN, SUMXN);
  k2_prep<<<NI * 64, 256, 0, stream>>>(in_W, conv_W, conv_b, xproj_W, dt_W, dt_b,
                                       XN, SX2, SDT2, SB2, SC2);
  k3a_seg<<<NI * 16, 256, 0, stream>>>(A_log, SDT2, SX2, SB2, Pp, Qp);
  k3b_comb<<<128, 256, 0, stream>>>(Pp, Qp);
  k3c_scan<<<NI * 16, 256, 0, stream>>>(A_log, SDT2, SX2, SB2, SC2, XN, in_W, D_p,
                                        Pp, YS2, SUMYF);
  k4_gates<<<NI, 64, 0, stream>>>(out_W, se_W1, se_W2, skip, SUMYF, SUMXN, GATES);
  k5b_combine<<<NI * 64, 256, 0, stream>>>(out_W, skip, GATES, YS2, XN);
  k6_ln_proj<<<B_ * 64, 256, 0, stream>>>(norm_g, norm_b, proj_W, proj_b, XN, out);
}

// Round 6
// 294.921 us; speedup vs baseline: 3.0489x; 1.1298x over previous
//
#include <hip/hip_runtime.h>
#include <math.h>

typedef _Float16 h16;

#define DEV static __device__ __forceinline__

constexpr int B_ = 8, C_ = 128, L_ = 4096, OUT_ = 128;
constexpr int NCH = 4, DM = 32, DS = 16, DI = 64;
constexpr int NI = 32;            // B_*NCH instances
constexpr int NSEG = 64;          // scan segments
constexpr int SL = L_ / NSEG;     // 64 steps per segment

DEV float sigmoidf_(float x) { return 1.f / (1.f + __expf(-x)); }
DEV float siluf_(float x) { return x * sigmoidf_(x); }
DEV float softplusf_(float x) { return (x > 20.f) ? x : __logf(1.f + __expf(x)); }

template <int CTRL>
DEV float dpp_add_(float x) {
  int v = __builtin_amdgcn_update_dpp(0, __float_as_int(x), CTRL, 0xf, 0xf, false);
  return x + __int_as_float(v);
}

// ---------------- K1: LayerNorm1 (B,C,L)->(B,L,C) + token sums ----------------
__global__ __launch_bounds__(256) void k1_ln(const float* __restrict__ x,
                                             const float* __restrict__ gn,
                                             const float* __restrict__ bn,
                                             float* __restrict__ XN,
                                             float* __restrict__ SUMXN) {
  int bid = blockIdx.x;
  int b = bid >> 6, tile = bid & 63;
  int t0 = tile * 64;
  int tid = threadIdx.x;
  __shared__ float xT[128][65];
  __shared__ float gnS[128], bnS[128];
  __shared__ float red[256];
  if (tid < 128) { gnS[tid] = gn[tid]; bnS[tid] = bn[tid]; }
  for (int k = tid; k < 8192; k += 256) {
    int c = k >> 6, tt = k & 63;
    xT[c][tt] = x[((size_t)(b * C_ + c)) * L_ + t0 + tt];
  }
  __syncthreads();
  {
    int tok = tid >> 2, q = tid & 3;
    float s = 0.f, qq = 0.f;
#pragma unroll
    for (int j = 0; j < 32; ++j) {
      float v = xT[q + 4 * j][tok];
      s += v; qq += v * v;
    }
    s = dpp_add_<0xB1>(s); qq = dpp_add_<0xB1>(qq);
    s = dpp_add_<0x4E>(s); qq = dpp_add_<0x4E>(qq);
    float m = s * (1.f / 128.f);
    float var = qq * (1.f / 128.f) - m * m;
    float rs = rsqrtf(var + 1e-5f);
#pragma unroll
    for (int j = 0; j < 32; ++j) {
      int c = q + 4 * j;
      float v = xT[c][tok];
      xT[c][tok] = (v - m) * rs * gnS[c] + bnS[c];
    }
  }
  __syncthreads();
  float acc = 0.f;
  int cfix = tid & 127;
  for (int k = tid; k < 8192; k += 256) {
    int tt = k >> 7, c = k & 127;
    float v = xT[c][tt];
    XN[((size_t)(b * L_ + t0 + tt)) * C_ + c] = v;
    acc += v;
  }
  red[tid] = acc;
  __syncthreads();
  if (tid < 128) atomicAdd(&SUMXN[b * C_ + cfix], red[tid] + red[tid + 128]);
}

// ---------------- K2: in-proj + conv + silu + x-proj + dt (t-major outputs) ----
// lane = token-row; weight reads are wave-uniform -> scalar (s_load) path.
__global__ __launch_bounds__(256) void k2_prep(
    const float* __restrict__ in_W, const float* __restrict__ conv_W,
    const float* __restrict__ conv_b, const float* __restrict__ xproj_W,
    const float* __restrict__ dt_W, const float* __restrict__ dt_b,
    const float* __restrict__ XN, h16* __restrict__ SX2, h16* __restrict__ SDT2,
    h16* __restrict__ SB2, h16* __restrict__ SC2) {
  int bid = blockIdx.x;
  int i = bid >> 6, tile = bid & 63;
  int b = i >> 2, ch = i & 3;
  int t0 = tile * 64;
  int tid = threadIdx.x;
  int w = __builtin_amdgcn_readfirstlane(tid >> 6);
  int lane = tid & 63;

  __shared__ float uS[67][33];      // stride 33: scalar access conflict-free
  __shared__ float preS[67][65];
  __shared__ float xdS[64][35];
  __shared__ float convWS[64][4];
  __shared__ float dtWS[64][2];
  __shared__ float dtbS[64], cbS[64];

  convWS[tid >> 2][tid & 3] = conv_W[tid];
  if (tid < 128) dtWS[tid >> 1][tid & 1] = dt_W[tid];
  if (tid < 64) { dtbS[tid] = dt_b[tid]; cbS[tid] = conv_b[tid]; }
  const float* xn = XN + (size_t)b * L_ * C_ + ch * DM;
  for (int k = tid; k < 67 * 32; k += 256) {
    int r = k >> 5, c = k & 31;
    int tg = t0 - 3 + r;
    uS[r][c] = (tg >= 0) ? xn[(size_t)tg * C_ + c] : 0.f;
  }
  __syncthreads();
  // u row for this thread's token-row into regs (2-way banks, free)
  float ur[32];
#pragma unroll
  for (int c = 0; c < 32; ++c) ur[c] = uS[lane][c];
  // in-proj: wave w covers d in [w*16, w*16+16); weights via scalar loads
  {
    int d0 = w * 16;
#pragma unroll 2
    for (int q = 0; q < 16; ++q) {
      int d = d0 + q;
      const float* wp = in_W + d * 32;   // wave-uniform -> s_load
      float a = 0.f;
#pragma unroll
      for (int c = 0; c < 32; ++c) a = fmaf(ur[c], wp[c], a);
      preS[lane][d] = a;                 // d uniform -> 2-way banks
    }
  }
  // halo rows 64..66: per-lane d, per-lane global weights (tiny, L2-hot)
  if (w < 3) {
    int rh = 64 + w;
    const float* wp = in_W + lane * 32;
    float a = 0.f;
#pragma unroll
    for (int c = 0; c < 32; ++c) a = fmaf(uS[rh][c], wp[c], a);  // uS broadcast
    preS[rh][lane] = a;
  }
  __syncthreads();
  // causal depthwise conv + silu (thread owns d=lane, 16 token-rows)
  float convv[16];
  {
    int idx = 0;
    for (int k = tid; k < 4096; k += 256, ++idx) {
      int r = k >> 6, d = k & 63;
      float v = cbS[d];
#pragma unroll
      for (int j = 0; j < 4; ++j) v = fmaf(convWS[d][j], preS[r + j][d], v);
      convv[idx] = siluf_(v);
    }
  }
  __syncthreads();
  {
    int idx = 0;
    for (int k = tid; k < 4096; k += 256, ++idx) {
      int r = k >> 6, d = k & 63;
      preS[r][d] = convv[idx];
    }
  }
  __syncthreads();
  // SX2 writeout: t-major [i][t][d]
  h16* SXp = SX2 + ((size_t)i * L_ + t0) * DI;
  for (int k = tid; k < 4096; k += 256) {
    int d = k & 63, r = k >> 6;
    SXp[(size_t)r * DI + d] = (h16)preS[r][d];
  }
  // x-proj: lane = token row; weights via scalar loads
  {
    int o0 = (w == 0) ? 0 : (w == 1) ? 9 : (w == 2) ? 18 : 26;
    int no = (w < 2) ? 9 : 8;
    float acc[9];
#pragma unroll
    for (int q = 0; q < 9; ++q) acc[q] = 0.f;
#pragma unroll
    for (int c0 = 0; c0 < 64; c0 += 32) {
      float xr[32];
#pragma unroll
      for (int c = 0; c < 32; ++c) xr[c] = preS[lane][c0 + c];
      for (int q = 0; q < 9; ++q) {
        if (q < no) {
          const float* wp = xproj_W + (o0 + q) * 64 + c0;  // uniform -> s_load
          float a = acc[q];
#pragma unroll
          for (int c = 0; c < 32; ++c) a = fmaf(xr[c], wp[c], a);
          acc[q] = a;
        }
      }
    }
#pragma unroll
    for (int q = 0; q < 9; ++q)
      if (q < no) xdS[lane][o0 + q] = acc[q];
  }
  __syncthreads();
  h16* SDTp = SDT2 + ((size_t)i * L_ + t0) * DI;
  for (int k = tid; k < 4096; k += 256) {
    int d = k & 63, r = k >> 6;
    float raw = fmaf(xdS[r][0], dtWS[d][0], fmaf(xdS[r][1], dtWS[d][1], dtbS[d]));
    SDTp[(size_t)r * DI + d] = (h16)softplusf_(raw);
  }
  h16* SBp = SB2 + ((size_t)i * L_ + t0) * DS;
  h16* SCp = SC2 + ((size_t)i * L_ + t0) * DS;
  for (int k = tid; k < 16 * 64; k += 256) {
    int s = k & 15, r = k >> 4;
    SBp[(size_t)r * DS + s] = (h16)xdS[r][2 + s];
    SCp[(size_t)r * DS + s] = (h16)xdS[r][18 + s];
  }
}

// ---------------- K3a: per-segment local scan (d-per-thread) -> (P, Q) ----------------
__global__ __launch_bounds__(256) void k3a_seg(
    const float* __restrict__ A_log, const h16* __restrict__ SDT2,
    const h16* __restrict__ SX2, const h16* __restrict__ SB2,
    float* __restrict__ Pp, float* __restrict__ Qp) {
  int bid = blockIdx.x;             // i*16 + sg4
  int i = bid >> 4, sg4 = bid & 15;
  int tid = threadIdx.x;
  int w = tid >> 6, lane = tid & 63;
  int seg = sg4 * 4 + w;
  int t0 = seg * SL;
  __shared__ float bS[4][64][20];
  {
    const h16* pb = SB2 + ((size_t)i * L_ + t0 + lane) * DS;
    float4 r0 = *(const float4*)pb;
    float4 r1 = *(const float4*)(pb + 8);
    const h16* h0p = (const h16*)&r0;
    const h16* h1p = (const h16*)&r1;
#pragma unroll
    for (int s = 0; s < 8; ++s) bS[w][lane][s] = (float)h0p[s];
#pragma unroll
    for (int s = 0; s < 8; ++s) bS[w][lane][8 + s] = (float)h1p[s];
  }
  __syncthreads();
  float Av[16];
#pragma unroll
  for (int s = 0; s < 16; ++s) Av[s] = -__expf(A_log[lane * 16 + s]);
  float A0 = Av[0];
  bool okf = true;
#pragma unroll
  for (int s = 0; s < 16; ++s) okf &= fabsf(Av[s] - (float)(s + 1) * A0) <= 1e-4f * fabsf(Av[s]);
  int fastp = __all(okf ? 1 : 0);
  float h[16];
#pragma unroll
  for (int s = 0; s < 16; ++s) h[s] = 0.f;
  float sdt = 0.f;
  const h16* pdt = SDT2 + ((size_t)i * L_ + t0) * DI + lane;
  const h16* pxx = SX2 + ((size_t)i * L_ + t0) * DI + lane;
  float dtc = (float)pdt[0], xvc = (float)pxx[0];
  for (int t = 0; t < SL; ++t) {
    float dt = dtc, xv = xvc;
    if (t < SL - 1) { dtc = (float)pdt[(t + 1) * DI]; xvc = (float)pxx[(t + 1) * DI]; }
    float Bv[16];
    const float* row = &bS[w][t][0];
#pragma unroll
    for (int j = 0; j < 4; ++j) *(float4*)&Bv[4 * j] = *(const float4*)(row + 4 * j);
    float dtx = dt * xv;
    float dA[16];
    if (fastp) {
      float E = __expf(A0 * dt);
      dA[0] = E;
#pragma unroll
      for (int s = 1; s < 16; ++s) dA[s] = dA[s - 1] * E;
    } else {
#pragma unroll
      for (int s = 0; s < 16; ++s) dA[s] = __expf(Av[s] * dt);
    }
#pragma unroll
    for (int s = 0; s < 16; ++s) h[s] = fmaf(dA[s], h[s], dtx * Bv[s]);
    sdt += dt;
  }
  float P[16];
  if (fastp) {
    float E = __expf(A0 * sdt);
    P[0] = E;
#pragma unroll
    for (int s = 1; s < 16; ++s) P[s] = P[s - 1] * E;
  } else {
#pragma unroll
    for (int s = 0; s < 16; ++s) P[s] = __expf(Av[s] * sdt);
  }
  size_t base = (((size_t)i * DI + lane) * NSEG + seg) * DS;
#pragma unroll
  for (int j = 0; j < 4; ++j) {
    *(float4*)(Pp + base + 4 * j) = *(float4*)&P[4 * j];
    *(float4*)(Qp + base + 4 * j) = *(float4*)&h[4 * j];
  }
}

// ---------------- K3b: inter-segment scan -> h0 per segment (overlays P) ----------------
__global__ __launch_bounds__(256) void k3b_comb(float* __restrict__ Pp,
                                                const float* __restrict__ Qp) {
  int g = blockIdx.x * 256 + threadIdx.x;  // 32768 = NI*DI*DS
  int s = g & 15;
  int r = g >> 4;          // over NI*DI
  size_t base = (size_t)r * NSEG * DS + s;
  float H = 0.f;
  for (int seg = 0; seg < NSEG; ++seg) {
    size_t a = base + (size_t)seg * DS;
    float P = Pp[a], Q = Qp[a];
    Pp[a] = H;
    H = fmaf(P, H, Q);
  }
}

// ---------------- K3c: final scan, fused with z-gate/D-term/token-sums ----------------
__global__ __launch_bounds__(256) void k3c_scan(
    const float* __restrict__ A_log, const h16* __restrict__ SDT2,
    const h16* __restrict__ SX2, const h16* __restrict__ SB2,
    const h16* __restrict__ SC2, const float* __restrict__ XN,
    const float* __restrict__ in_W, const float* __restrict__ D_p,
    const float* __restrict__ H0p, h16* __restrict__ YS2,
    float* __restrict__ SUMYF) {
  int bid = blockIdx.x;             // i*16 + sg4
  int i = bid >> 4, sg4 = bid & 15;
  int b = i >> 2, ch = i & 3;
  int tid = threadIdx.x;
  int w = tid >> 6, lane = tid & 63;
  int seg = sg4 * 4 + w;
  int t0 = seg * SL;
  __shared__ float rowS[4][64][68];   // [w][t][ B16 | C16 | u32 ] + pad
  {
    const h16* pb = SB2 + ((size_t)i * L_ + t0 + lane) * DS;
    const h16* pc = SC2 + ((size_t)i * L_ + t0 + lane) * DS;
    float4 r0 = *(const float4*)pb;
    float4 r1 = *(const float4*)(pb + 8);
    float4 r2 = *(const float4*)pc;
    float4 r3 = *(const float4*)(pc + 8);
    const h16* hp0 = (const h16*)&r0;
    const h16* hp1 = (const h16*)&r1;
    const h16* hp2 = (const h16*)&r2;
    const h16* hp3 = (const h16*)&r3;
#pragma unroll
    for (int s = 0; s < 8; ++s) {
      rowS[w][lane][s] = (float)hp0[s];
      rowS[w][lane][8 + s] = (float)hp1[s];
      rowS[w][lane][16 + s] = (float)hp2[s];
      rowS[w][lane][24 + s] = (float)hp3[s];
    }
    const float* pu = XN + ((size_t)(b * L_ + t0 + lane)) * C_ + ch * DM;
#pragma unroll
    for (int j = 0; j < 8; ++j)
      *(float4*)&rowS[w][lane][32 + 4 * j] = *(const float4*)(pu + 4 * j);
  }
  __syncthreads();
  float Av[16];
#pragma unroll
  for (int s = 0; s < 16; ++s) Av[s] = -__expf(A_log[lane * 16 + s]);
  float A0 = Av[0];
  bool okf = true;
#pragma unroll
  for (int s = 0; s < 16; ++s) okf &= fabsf(Av[s] - (float)(s + 1) * A0) <= 1e-4f * fabsf(Av[s]);
  int fastp = __all(okf ? 1 : 0);
  float4 wz[8];
#pragma unroll
  for (int j = 0; j < 8; ++j) wz[j] = *(const float4*)(in_W + 2048 + lane * 32 + 4 * j);
  float Dp = D_p[lane];
  float h[16];
  {
    size_t base = (((size_t)i * DI + lane) * NSEG + seg) * DS;
#pragma unroll
    for (int j = 0; j < 4; ++j) *(float4*)&h[4 * j] = *(const float4*)(H0p + base + 4 * j);
  }
  const h16* pdt = SDT2 + ((size_t)i * L_ + t0) * DI + lane;
  const h16* pxx = SX2 + ((size_t)i * L_ + t0) * DI + lane;
  h16* pys = YS2 + ((size_t)i * L_ + t0) * DI + lane;
  float dtc = (float)pdt[0], xvc = (float)pxx[0];
  float sum = 0.f;
  for (int t = 0; t < SL; ++t) {
    float dt = dtc, xv = xvc;
    if (t < SL - 1) { dtc = (float)pdt[(t + 1) * DI]; xvc = (float)pxx[(t + 1) * DI]; }
    const float* row = &rowS[w][t][0];
    float Bv[16], Cv[16];
#pragma unroll
    for (int j = 0; j < 4; ++j) {
      *(float4*)&Bv[4 * j] = *(const float4*)(row + 4 * j);
      *(float4*)&Cv[4 * j] = *(const float4*)(row + 16 + 4 * j);
    }
    float dtx = dt * xv;
    float dA[16];
    if (fastp) {
      float E = __expf(A0 * dt);
      dA[0] = E;
#pragma unroll
      for (int s = 1; s < 16; ++s) dA[s] = dA[s - 1] * E;
    } else {
#pragma unroll
      for (int s = 0; s < 16; ++s) dA[s] = __expf(Av[s] * dt);
    }
    float y = 0.f;
#pragma unroll
    for (int s = 0; s < 16; ++s) {
      h[s] = fmaf(dA[s], h[s], dtx * Bv[s]);
      y = fmaf(h[s], Cv[s], y);
    }
    float z = 0.f;
#pragma unroll
    for (int j = 0; j < 8; ++j) {
      float4 u4 = *(const float4*)(row + 32 + 4 * j);
      z = fmaf(u4.x, wz[j].x, z);
      z = fmaf(u4.y, wz[j].y, z);
      z = fmaf(u4.z, wz[j].z, z);
      z = fmaf(u4.w, wz[j].w, z);
    }
    float yf = (y + xv * Dp) * siluf_(z);
    pys[(size_t)t * DI] = (h16)yf;
    sum += yf;
  }
  atomicAdd(&SUMYF[i * DI + lane], sum);
}

// ---------------- K4: SE gates ----------------
__global__ __launch_bounds__(64) void k4_gates(
    const float* __restrict__ out_W, const float* __restrict__ se_W1,
    const float* __restrict__ se_W2, const float* __restrict__ skip_p,
    const float* __restrict__ SUMYF, const float* __restrict__ SUMXN,
    float* __restrict__ GATES) {
  int i = blockIdx.x;
  int b = i >> 2, ch = i & 3;
  int tid = threadIdx.x;
  __shared__ float syS[64], catS[64], seS[2];
  syS[tid] = SUMYF[i * DI + tid];
  __syncthreads();
  float invL = 1.f / (float)L_;
  if (tid < 32) {
    float acc = 0.f;
#pragma unroll
    for (int dd = 0; dd < 64; ++dd) acc = fmaf(syS[dd], out_W[tid * 64 + dd], acc);
    catS[tid] = acc * invL;
  } else {
    int c = tid - 32;
    catS[tid] = skip_p[0] * SUMXN[b * C_ + ch * DM + c] * invL;
  }
  __syncthreads();
  if (tid < 2) {
    float acc = 0.f;
#pragma unroll
    for (int k = 0; k < 64; ++k) acc = fmaf(catS[k], se_W1[tid * 64 + k], acc);
    seS[tid] = fmaxf(acc, 0.f);
  }
  __syncthreads();
  float gg = fmaf(seS[0], se_W2[tid * 2 + 0], seS[1] * se_W2[tid * 2 + 1]);
  GATES[i * DI + tid] = sigmoidf_(gg);
}

// ---------------- K5b: M1 = yfull @ outW.T, gated combine (in place over xn) ----------------
__global__ __launch_bounds__(256) void k5b_combine(
    const float* __restrict__ out_W, const float* __restrict__ skip_p,
    const float* __restrict__ GATES, const h16* __restrict__ YS2,
    float* __restrict__ XN) {
  int bid = blockIdx.x;
  int i = bid >> 6, tile = bid & 63;
  int b = i >> 2, ch = i & 3;
  int t0 = tile * 64;
  int tid = threadIdx.x;
  int w = tid >> 6, lane = tid & 63;
  __shared__ float outWS[32][68];
  __shared__ float yfT[64][65];
  __shared__ float xnS[64][37];
  __shared__ float gS[64];
  for (int k = tid; k < 2048; k += 256) outWS[k >> 6][k & 63] = out_W[k];
  if (tid < 64) gS[tid] = GATES[i * DI + tid];
  const h16* py = YS2 + ((size_t)i * L_ + t0) * DI;
  for (int k = tid; k < 4096; k += 256) {
    int dd = k & 63, tt = k >> 6;
    yfT[tt][dd] = (float)py[(size_t)tt * DI + dd];
  }
  float* xn = XN + (size_t)b * L_ * C_ + ch * DM;
  for (int k = tid; k < 2048; k += 256) {
    int tt = k >> 5, o = k & 31;
    xnS[tt][o] = xn[(size_t)(t0 + tt) * C_ + o];
  }
  __syncthreads();
  float yr[64];
#pragma unroll
  for (int dd = 0; dd < 64; ++dd) yr[dd] = yfT[lane][dd];
  float skip = skip_p[0];
#pragma unroll
  for (int q = 0; q < 8; ++q) {
    int o = w * 8 + q;
    float a = 0.f;
#pragma unroll
    for (int d4 = 0; d4 < 64; d4 += 4) {
      float4 wv = *(const float4*)&outWS[o][d4];
      a = fmaf(yr[d4], wv.x, a);
      a = fmaf(yr[d4 + 1], wv.y, a);
      a = fmaf(yr[d4 + 2], wv.z, a);
      a = fmaf(yr[d4 + 3], wv.w, a);
    }
    xnS[lane][o] = gS[o] * a + gS[32 + o] * skip * xnS[lane][o];
  }
  __syncthreads();
  for (int k = tid; k < 2048; k += 256) {
    int tt = k >> 5, o = k & 31;
    xn[(size_t)(t0 + tt) * C_ + o] = xnS[tt][o];
  }
}

// ---------------- K6: LN2 + proj + transpose to (B,OUT,H,W) ----------------
__global__ __launch_bounds__(256) void k6_ln_proj(
    const float* __restrict__ gn, const float* __restrict__ bn,
    const float* __restrict__ proj_W, const float* __restrict__ proj_b,
    const float* __restrict__ XN, float* __restrict__ out) {
  int bid = blockIdx.x;
  int b = bid >> 6, tile = bid & 63;
  int t0 = tile * 64;
  int tid = threadIdx.x;
  int w = tid >> 6, lane = tid & 63;
  __shared__ float xmS[64][132];
  __shared__ float projS[64][132];
  __shared__ float gnS[128], bnS[128];
  if (tid < 128) { gnS[tid] = gn[tid]; bnS[tid] = bn[tid]; }
  const float* xm = XN + (size_t)b * L_ * C_;
  for (int k = tid; k < 8192; k += 256) {
    int tt = k >> 7, c = k & 127;
    xmS[tt][c] = xm[(size_t)(t0 + tt) * C_ + c];
  }
  for (int k = tid; k < 8192; k += 256) {
    int o = k >> 7, c = k & 127;
    projS[o][c] = proj_W[k];
  }
  __syncthreads();
  {
    int tok = tid >> 2, q = tid & 3;
    float s = 0.f, qq = 0.f;
#pragma unroll
    for (int j = 0; j < 32; ++j) {
      float v = xmS[tok][4 * j + q];
      s += v; qq += v * v;
    }
    s = dpp_add_<0xB1>(s); qq = dpp_add_<0xB1>(qq);
    s = dpp_add_<0x4E>(s); qq = dpp_add_<0x4E>(qq);
    float m = s * (1.f / 128.f);
    float var = qq * (1.f / 128.f) - m * m;
    float rs = rsqrtf(var + 1e-5f);
#pragma unroll
    for (int j = 0; j < 32; ++j) {
      int c = 4 * j + q;
      float v = xmS[tok][c];
      xmS[tok][c] = (v - m) * rs * gnS[c] + bnS[c];
    }
  }
  __syncthreads();
  int lt = lane >> 2, lo = lane & 3;
  for (int phase = 0; phase < 2; ++phase) {
    if (phase == 1) {
      __syncthreads();
      for (int k = tid; k < 8192; k += 256) {
        int o = k >> 7, c = k & 127;
        projS[o][c] = proj_W[8192 + k];
      }
      __syncthreads();
    }
    int obase = phase * 64 + w * 16 + lo * 4;
    float acc[16];
#pragma unroll
    for (int j = 0; j < 4; ++j)
#pragma unroll
      for (int oi = 0; oi < 4; ++oi) acc[j * 4 + oi] = proj_b[obase + oi];
#pragma unroll 4
    for (int c0 = 0; c0 < 128; c0 += 4) {
      float4 xr[4], pr[4];
#pragma unroll
      for (int j = 0; j < 4; ++j) xr[j] = *(const float4*)&xmS[lt * 4 + j][c0];
#pragma unroll
      for (int oi = 0; oi < 4; ++oi) pr[oi] = *(const float4*)&projS[w * 16 + lo * 4 + oi][c0];
#pragma unroll
      for (int j = 0; j < 4; ++j)
#pragma unroll
        for (int oi = 0; oi < 4; ++oi) {
          float a = acc[j * 4 + oi];
          a = fmaf(xr[j].x, pr[oi].x, a);
          a = fmaf(xr[j].y, pr[oi].y, a);
          a = fmaf(xr[j].z, pr[oi].z, a);
          a = fmaf(xr[j].w, pr[oi].w, a);
          acc[j * 4 + oi] = a;
        }
    }
#pragma unroll
    for (int oi = 0; oi < 4; ++oi) {
      int o = obase + oi;
      float4 v = make_float4(acc[0 * 4 + oi], acc[1 * 4 + oi],
                             acc[2 * 4 + oi], acc[3 * 4 + oi]);
      *(float4*)&out[((size_t)(b * OUT_ + o)) * L_ + t0 + lt * 4] = v;
    }
  }
}

extern "C" void kernel_launch(void* const* d_in, const int* in_sizes, int n_in,
                              void* d_out, int out_size, void* d_ws, size_t ws_size,
                              hipStream_t stream) {
  const float* x = (const float*)d_in[0];
  const float* norm_g = (const float*)d_in[1];
  const float* norm_b = (const float*)d_in[2];
  const float* proj_W = (const float*)d_in[3];
  const float* proj_b = (const float*)d_in[4];
  const float* skip = (const float*)d_in[5];
  const float* se_W1 = (const float*)d_in[6];
  const float* se_W2 = (const float*)d_in[7];
  const float* in_W = (const float*)d_in[8];
  const float* conv_W = (const float*)d_in[9];
  const float* conv_b = (const float*)d_in[10];
  const float* xproj_W = (const float*)d_in[11];
  const float* dt_W = (const float*)d_in[12];
  const float* dt_b = (const float*)d_in[13];
  const float* A_log = (const float*)d_in[14];
  const float* D_p = (const float*)d_in[15];
  const float* out_W = (const float*)d_in[16];
  float* out = (float*)d_out;

  // workspace (~92 MiB)
  float* XN = (float*)d_ws;                         // B*L*C f32
  float* SUMYF = XN + (size_t)B_ * L_ * C_;         // NI*DI
  float* SUMXN = SUMYF + NI * DI;                   // B*C
  float* GATES = SUMXN + B_ * C_;                   // NI*DI
  float* Pp = GATES + NI * DI;                      // NI*DI*NSEG*DS f32
  float* Qp = Pp + (size_t)NI * DI * NSEG * DS;
  h16* YS2 = (h16*)(Qp + (size_t)NI * DI * NSEG * DS);  // NI*L*DI h16
  h16* SX2 = YS2 + (size_t)NI * L_ * DI;
  h16* SDT2 = SX2 + (size_t)NI * L_ * DI;
  h16* SB2 = SDT2 + (size_t)NI * L_ * DI;           // NI*L*DS h16
  h16* SC2 = SB2 + (size_t)NI * L_ * DS;

  hipMemsetAsync(SUMYF, 0, (size_t)(NI * DI + B_ * C_) * sizeof(float), stream);
  k1_ln<<<B_ * 64, 256, 0, stream>>>(x, norm_g, norm_b, XN, SUMXN);
  k2_prep<<<NI * 64, 256, 0, stream>>>(in_W, conv_W, conv_b, xproj_W, dt_W, dt_b,
                                       XN, SX2, SDT2, SB2, SC2);
  k3a_seg<<<NI * 16, 256, 0, stream>>>(A_log, SDT2, SX2, SB2, Pp, Qp);
  k3b_comb<<<128, 256, 0, stream>>>(Pp, Qp);
  k3c_scan<<<NI * 16, 256, 0, stream>>>(A_log, SDT2, SX2, SB2, SC2, XN, in_W, D_p,
                                        Pp, YS2, SUMYF);
  k4_gates<<<NI, 64, 0, stream>>>(out_W, se_W1, se_W2, skip, SUMYF, SUMXN, GATES);
  k5b_combine<<<NI * 64, 256, 0, stream>>>(out_W, skip, GATES, YS2, XN);
  k6_ln_proj<<<B_ * 64, 256, 0, stream>>>(norm_g, norm_b, proj_W, proj_b, XN, out);
}